// Round 1
// 437.374 us; speedup vs baseline: 1.0400x; 1.0400x over previous
//
#include <hip/hip_runtime.h>
#include <stdint.h>

// ---------- types ----------
typedef __bf16    bf16x8 __attribute__((ext_vector_type(8)));
typedef float     f32x4  __attribute__((ext_vector_type(4)));
typedef _Float16  f16;
typedef _Float16  f16x2  __attribute__((ext_vector_type(2)));
typedef _Float16  f16x4  __attribute__((ext_vector_type(4)));
typedef _Float16  f16x8  __attribute__((ext_vector_type(8)));

#define DEV __device__ __forceinline__

DEV ushort f2bf(float f) {               // RTNE float -> bf16 bits
  union { float f; uint32_t u; } v; v.f = f;
  uint32_t u = v.u;
  return (ushort)((u + 0x7fffu + ((u >> 16) & 1u)) >> 16);
}

DEV f16x2 cvt_pkrtz(float a, float b) {  // v_cvt_pkrtz_f16_f32, bit-cast to f16x2
  return __builtin_bit_cast(f16x2, __builtin_amdgcn_cvt_pkrtz(a, b));
}

// async global->LDS, 16B per lane. LDS dest must be wave-uniform base + lane*16.
DEV void async16(const void* g, void* l) {
  __builtin_amdgcn_global_load_lds(
      (__attribute__((address_space(1))) void*)(uintptr_t)g,
      (__attribute__((address_space(3))) void*)(uint32_t)(uintptr_t)l,
      16, 0, 0);
}

// ---------- prep kernel: mod-gemm + weight split/cast + wo cast (one launch) ----
__global__ __launch_bounds__(256)
void prep_kernel(const float* __restrict__ t, const float* __restrict__ mw,
                 float* __restrict__ mod,
                 const float* __restrict__ qkvw, ushort* __restrict__ wqk,
                 ushort* __restrict__ wv,
                 const float* __restrict__ wow, ushort* __restrict__ wowb) {
  const int id = blockIdx.x;
  const int tid = threadIdx.x;
  if (id < 2048) {
    // mod = t @ mod_w.T : column j, wave w handles batches w*4..w*4+3
    const int j = id;
    const int w = tid >> 6, lane = tid & 63;
    float wr[16];
#pragma unroll
    for (int i = 0; i < 16; ++i) wr[i] = mw[(size_t)j * 1024 + lane + i * 64];
#pragma unroll
    for (int bb = 0; bb < 4; ++bb) {
      int b = w * 4 + bb;
      float s = 0.f;
#pragma unroll
      for (int i = 0; i < 16; ++i) s += wr[i] * t[b * 1024 + lane + i * 64];
#pragma unroll
      for (int m = 32; m >= 1; m >>= 1) s += __shfl_xor(s, m, 64);
      if (lane == 0) mod[b * 2048 + j] = s;
    }
  } else if (id < 5120) {
    // split qkv_w row j -> wqk (q,k interleaved per head) or wv
    const int j = id - 2048;
    uint32_t hd = (uint32_t)j / 192u;
    uint32_t rem = (uint32_t)j - hd * 192u;
    ushort* dst = (rem < 128u) ? (wqk + (size_t)(hd * 128u + rem) * 1024)
                               : (wv + (size_t)(hd * 64u + (rem - 128u)) * 1024);
    float4 v = ((const float4*)(qkvw + (size_t)j * 1024))[tid];
    ushort4 o;
    o.x = f2bf(v.x); o.y = f2bf(v.y); o.z = f2bf(v.z); o.w = f2bf(v.w);
    ((ushort4*)dst)[tid] = o;
  } else {
    // wo cast: 1024 blocks x 256 thr x float4
    const int i = (id - 5120) * 256 + tid;   // < 262144
    float4 v = ((const float4*)wow)[i];
    ushort4 o;
    o.x = f2bf(v.x); o.y = f2bf(v.y); o.z = f2bf(v.z); o.w = f2bf(v.w);
    ((ushort4*)wowb)[i] = o;
  }
}

// ---------- RMSNorm + modulate -> bf16 h ----------
__global__ __launch_bounds__(256)
void rms_mod_kernel(const float* __restrict__ x, const float* __restrict__ nw,
                    const float* __restrict__ mod, ushort* __restrict__ h) {
  int row = blockIdx.x;
  int b = row >> 10;
  int tid = threadIdx.x;
  const float4 xv = *(const float4*)(x + (size_t)row * 1024 + tid * 4);
  float ss = xv.x * xv.x + xv.y * xv.y + xv.z * xv.z + xv.w * xv.w;
#pragma unroll
  for (int m = 32; m >= 1; m >>= 1) ss += __shfl_xor(ss, m, 64);
  __shared__ float red[4];
  int w = tid >> 6, lane = tid & 63;
  if (lane == 0) red[w] = ss;
  __syncthreads();
  float tot = red[0] + red[1] + red[2] + red[3];
  float rn = rsqrtf(tot * (1.f / 1024.f) + 1e-6f);
  float4 wv = *(const float4*)(nw + tid * 4);
  float4 sc = *(const float4*)(mod + (size_t)b * 2048 + tid * 4);
  float4 sh = *(const float4*)(mod + (size_t)b * 2048 + 1024 + tid * 4);
  ushort4 o;
  o.x = f2bf(xv.x * rn * wv.x * (1.f + sc.x) + sh.x);
  o.y = f2bf(xv.y * rn * wv.y * (1.f + sc.y) + sh.y);
  o.z = f2bf(xv.z * rn * wv.z * (1.f + sc.z) + sh.z);
  o.w = f2bf(xv.w * rn * wv.w * (1.f + sc.w) + sh.w);
  *(ushort4*)(h + (size_t)row * 1024 + tid * 4) = o;
}

// ---------- QKV GEMM v2: 256x256 tile, BK=64, 8 waves, 4-phase deep pipeline ----
// mode1 = q/k proj + fused RoPE, mode2 = V^T.  C[M][N] = A[M][K] * B[N][K]^T.
// LDS: As dbuf 2x32KB + Bs dbuf 2x32KB = 128KB. Swizzle: 16B chunk ch ^= (row&7)
// (rows are 128B = exact bank wrap), applied on pre-swizzled global source
// (global_load_lds writes linearly) and on ds_read addresses.
__global__ __launch_bounds__(512, 2)
void gemm_qkv_kernel(const ushort* __restrict__ hbuf, const ushort* __restrict__ wqk,
                     const ushort* __restrict__ wvw,
                     f16* __restrict__ qb, f16* __restrict__ kb,
                     f16* __restrict__ vtb) {
  __shared__ ushort smem[65536];          // 128 KB
  const int id0 = blockIdx.x;
  const int id = (id0 & 7) * 96 + (id0 >> 3);   // XCD swizzle (768 % 8 == 0)
  int mode, m0, n0;
  const ushort *A, *B;
  if (id < 512) {                         // q/k: M=16384 tokens, N=2048 qk-rows
    mode = 1; m0 = (id >> 3) * 256; n0 = (id & 7) * 256; A = hbuf; B = wqk;
  } else {                                // V^T: M=1024 features, N=16384 tokens
    const int i2 = id - 512;
    mode = 2; n0 = (i2 >> 2) * 256; m0 = (i2 & 3) * 256; A = wvw; B = hbuf;
  }
  const int tid = threadIdx.x;
  const int w = tid >> 6, lane = tid & 63, quad = lane >> 4, l15 = lane & 15;
  const int wm = w >> 2, wn = w & 3;      // 2 x 4 wave grid; per-wave C: 128x64

  // ---- staging addresses: dest linear (row=tid>>3 (+64*i +128*h), ch=tid&7),
  //      source chunk pre-swizzled: sch = ch ^ (row&7) ----
  const int srow = tid >> 3;
  const int sch  = (tid & 7) ^ (srow & 7);
  const int soff = srow * 1024 + sch * 8;           // elems into operand panel
  const ushort* const Abase = A + (size_t)m0 * 1024;
  const ushort* const Bbase = B + (size_t)n0 * 1024;
  ushort* const As0 = smem;                         // 2 x 16384 ushort
  ushort* const Bs0 = smem + 32768;                 // 2 x 16384 ushort
  const int sdst = tid * 8;                         // ushort offset, lane*16B

#define STG_A(d, t, h) do { \
    async16(Abase + (h) * 131072 + soff + (t) * 64,          As0 + (d) * 16384 + (h) * 8192 + sdst); \
    async16(Abase + (h) * 131072 + 65536 + soff + (t) * 64,  As0 + (d) * 16384 + (h) * 8192 + 4096 + sdst); } while (0)
#define STG_B(d, t, h) do { \
    async16(Bbase + (h) * 131072 + soff + (t) * 64,          Bs0 + (d) * 16384 + (h) * 8192 + sdst); \
    async16(Bbase + (h) * 131072 + 65536 + soff + (t) * 64,  Bs0 + (d) * 16384 + (h) * 8192 + 4096 + sdst); } while (0)

  // ---- fragment read offsets (ushort units), swizzled chunk ----
  int aoff[2], boff[2];
#pragma unroll
  for (int kk = 0; kk < 2; ++kk) {
    const int swz = (((kk * 4 + quad) ^ (l15 & 7)) * 8);
    aoff[kk] = (wm * 128 + l15) * 64 + swz;
    boff[kk] = (wn * 64 + l15) * 64 + swz;
  }

  const f32x4 fzero = {0.f, 0.f, 0.f, 0.f};
  f32x4 acc[8][4];
#pragma unroll
  for (int a = 0; a < 8; ++a)
#pragma unroll
    for (int b = 0; b < 4; ++b) acc[a][b] = fzero;

  // ---- prologue: stage tile 0 into buf 0 ----
  STG_A(0, 0, 0); STG_A(0, 0, 1); STG_B(0, 0, 0); STG_B(0, 0, 1);
  asm volatile("s_waitcnt vmcnt(0)" ::: "memory");
  __builtin_amdgcn_s_barrier();

  bf16x8 af[4][2];   // current A half (4 m-frags x 2 k-steps)
  bf16x8 bfv[2][2];  // current B nh (2 n-frags x 2 k-steps)
#pragma unroll 2
  for (int t = 0; t < 16; ++t) {
    const int cur = t & 1, nxt = cur ^ 1;
    const int tn = (t < 15) ? t + 1 : 15;   // last iter re-stages harmlessly
    const ushort* Asc = As0 + cur * 16384;
    const ushort* Bsc = Bs0 + cur * 16384;

    // ---- phase 0: read A-mh0 + B-nh0; stage A-h0(t+1); mfma quad (0,0) ----
#pragma unroll
    for (int mf = 0; mf < 4; ++mf)
#pragma unroll
      for (int kk = 0; kk < 2; ++kk)
        af[mf][kk] = *(const bf16x8*)(Asc + mf * 1024 + aoff[kk]);
#pragma unroll
    for (int nf = 0; nf < 2; ++nf)
#pragma unroll
      for (int kk = 0; kk < 2; ++kk)
        bfv[nf][kk] = *(const bf16x8*)(Bsc + nf * 1024 + boff[kk]);
    STG_A(nxt, tn, 0);
    __builtin_amdgcn_s_barrier();
    __builtin_amdgcn_s_setprio(1);
#pragma unroll
    for (int mf = 0; mf < 4; ++mf)
#pragma unroll
      for (int nf = 0; nf < 2; ++nf)
#pragma unroll
        for (int kk = 0; kk < 2; ++kk)
          acc[mf][nf] = __builtin_amdgcn_mfma_f32_16x16x32_bf16(
              af[mf][kk], bfv[nf][kk], acc[mf][nf], 0, 0, 0);
    __builtin_amdgcn_s_setprio(0);
    __builtin_amdgcn_s_barrier();

    // ---- phase 1: read A-mh1; stage A-h1; mfma quad (1,0) ----
#pragma unroll
    for (int mf = 0; mf < 4; ++mf)
#pragma unroll
      for (int kk = 0; kk < 2; ++kk)
        af[mf][kk] = *(const bf16x8*)(Asc + (4 + mf) * 1024 + aoff[kk]);
    STG_A(nxt, tn, 1);
    __builtin_amdgcn_s_barrier();
    __builtin_amdgcn_s_setprio(1);
#pragma unroll
    for (int mf = 0; mf < 4; ++mf)
#pragma unroll
      for (int nf = 0; nf < 2; ++nf)
#pragma unroll
        for (int kk = 0; kk < 2; ++kk)
          acc[4 + mf][nf] = __builtin_amdgcn_mfma_f32_16x16x32_bf16(
              af[mf][kk], bfv[nf][kk], acc[4 + mf][nf], 0, 0, 0);
    __builtin_amdgcn_s_setprio(0);
    __builtin_amdgcn_s_barrier();

    // ---- phase 2: read B-nh1; stage B-h0; mfma quad (1,1) ----
#pragma unroll
    for (int nf = 0; nf < 2; ++nf)
#pragma unroll
      for (int kk = 0; kk < 2; ++kk)
        bfv[nf][kk] = *(const bf16x8*)(Bsc + (2 + nf) * 1024 + boff[kk]);
    STG_B(nxt, tn, 0);
    __builtin_amdgcn_s_barrier();
    __builtin_amdgcn_s_setprio(1);
#pragma unroll
    for (int mf = 0; mf < 4; ++mf)
#pragma unroll
      for (int nf = 0; nf < 2; ++nf)
#pragma unroll
        for (int kk = 0; kk < 2; ++kk)
          acc[4 + mf][2 + nf] = __builtin_amdgcn_mfma_f32_16x16x32_bf16(
              af[mf][kk], bfv[nf][kk], acc[4 + mf][2 + nf], 0, 0, 0);
    __builtin_amdgcn_s_setprio(0);
    __builtin_amdgcn_s_barrier();

    // ---- phase 3: re-read A-mh0; stage B-h1; mfma quad (0,1); tile wait ----
#pragma unroll
    for (int mf = 0; mf < 4; ++mf)
#pragma unroll
      for (int kk = 0; kk < 2; ++kk)
        af[mf][kk] = *(const bf16x8*)(Asc + mf * 1024 + aoff[kk]);
    STG_B(nxt, tn, 1);
    __builtin_amdgcn_s_barrier();
    __builtin_amdgcn_s_setprio(1);
#pragma unroll
    for (int mf = 0; mf < 4; ++mf)
#pragma unroll
      for (int nf = 0; nf < 2; ++nf)
#pragma unroll
        for (int kk = 0; kk < 2; ++kk)
          acc[mf][2 + nf] = __builtin_amdgcn_mfma_f32_16x16x32_bf16(
              af[mf][kk], bfv[nf][kk], acc[mf][2 + nf], 0, 0, 0);
    __builtin_amdgcn_s_setprio(0);
    asm volatile("s_waitcnt vmcnt(0)" ::: "memory");   // tile t+1 landed
    __builtin_amdgcn_s_barrier();
  }
#undef STG_A
#undef STG_B

  // ---- epilogue: wave-private LDS transpose (128x64) -> full-line stores ----
  ushort* eps = smem + w * 8192;          // 16 KB per wave, 8 waves = all 128 KB
#pragma unroll
  for (int mf = 0; mf < 8; ++mf)
#pragma unroll
    for (int nf = 0; nf < 4; ++nf)
#pragma unroll
      for (int r = 0; r < 4; ++r) {
        const int row_loc = mf * 16 + quad * 4 + r;
        const int col = nf * 16 + l15;
        const int ch = (col >> 3) ^ (row_loc & 7);
        union { f16 h; ushort u; } cv;
        cv.h = (f16)acc[mf][nf][r];
        eps[row_loc * 64 + ch * 8 + (col & 7)] = cv.u;
      }

  const int ch = lane & 7;
  const int rbase = lane >> 3;
  const int gcol = n0 + wn * 64;
  if (mode == 1) {
    const int hd = gcol >> 7, part = (gcol >> 6) & 1;
    const float QS = part ? 1.f : 0.125f * 1.44269504f;   // q: scale*log2e fold
    f16* const outp = part ? kb : qb;
    float th[4];
#pragma unroll
    for (int t2 = 0; t2 < 4; ++t2)
      th[t2] = __expf(-(float)((ch * 4 + t2) & 15) * 0.5756462732485114f); // ln(1e4)/16
#pragma unroll
    for (int i = 0; i < 16; ++i) {
      const int row_loc = i * 8 + rbase;
      union { uint4 u4; f16 h[8]; } uv;
      uv.u4 = *(const uint4*)(eps + row_loc * 64 + ((ch ^ (row_loc & 7)) * 8));
      const int m = m0 + wm * 128 + row_loc;   // token index
      const int n = m & 1023;
      const float xpos = (float)(n & 31), ypos = (float)(n >> 5);
#pragma unroll
      for (int t2 = 0; t2 < 4; ++t2) {
        const int p = ch * 4 + t2;
        const float pos = (p < 16) ? xpos : ypos;
        float sn, cs;
        __sincosf(pos * th[t2], &sn, &cs);
        const float x0 = (float)uv.h[2 * t2], x1 = (float)uv.h[2 * t2 + 1];
        f16x2 ro = cvt_pkrtz((x0 * cs - x1 * sn) * QS, (x1 * cs + x0 * sn) * QS);
        uv.h[2 * t2] = ro[0];
        uv.h[2 * t2 + 1] = ro[1];
      }
      f16* dst = outp + (((size_t)((m >> 10) * 16 + hd) * 1024 + n) * 64 + ch * 8);
      *(uint4*)dst = uv.u4;
    }
  } else {
    const int b = gcol >> 10, tb = gcol & 1023;
#pragma unroll
    for (int i = 0; i < 16; ++i) {
      const int row_loc = i * 8 + rbase;
      const uint4 v = *(const uint4*)(eps + row_loc * 64 + ((ch ^ (row_loc & 7)) * 8));
      const int m = m0 + wm * 128 + row_loc;   // feature row
      f16* dst = vtb + ((size_t)(b * 1024 + m) * 1024 + tb + ch * 8);
      *(uint4*)dst = v;
    }
  }
}

// ---------- WO GEMM: out[16384][1024] fp32 = abuf(head-major) @ wow^T ----------
__global__ __launch_bounds__(256, 3)
void gemm_wo_kernel(const ushort* __restrict__ A, const ushort* __restrict__ B,
                    float* __restrict__ outf) {
  __shared__ ushort smem[8192];
  ushort* As = smem;
  ushort* Bs = smem + 4096;
  const int K = 1024;
  const int m0 = blockIdx.y * 128, n0 = blockIdx.x * 128;
  const int tid = threadIdx.x;
  const int w = tid >> 6, lane = tid & 63, quad = lane >> 4, l15 = lane & 15;
  const int wm = (w >> 1) * 64, wn = (w & 1) * 64;
  const f32x4 fzero = {0.f, 0.f, 0.f, 0.f};
  f32x4 acc[4][4];
#pragma unroll
  for (int a = 0; a < 4; ++a)
#pragma unroll
    for (int b = 0; b < 4; ++b) acc[a][b] = fzero;

  const int s0 = tid, s1 = 256 + tid;
  const int r0 = s0 >> 2, c0 = (s0 & 3) ^ ((r0 >> 1) & 3);
  const int r1 = s1 >> 2, c1 = (s1 & 3) ^ ((r1 >> 1) & 3);
  // head-major abuf: elem(token m, k) at ((b*16 + (k>>6))*1024 + n)*64 + (k&63)
  const int b0 = m0 >> 10, nb = m0 & 1023;
  const size_t Abase = (size_t)b0 * 16 * 1024 * 64;
  const ushort* Ag0 = A + Abase + (size_t)(nb + r0) * 64 + c0 * 8;
  const ushort* Ag1 = A + Abase + (size_t)(nb + r1) * 64 + c1 * 8;
  const ushort* Bg0 = B + (size_t)(n0 + r0) * K + c0 * 8;
  const ushort* Bg1 = B + (size_t)(n0 + r1) * K + c1 * 8;

  for (int kt = 0; kt < K; kt += 32) {
    const size_t ka = (size_t)(kt >> 6) * 65536 + (size_t)(kt & 63);
    async16(Ag0 + ka, As + s0 * 8);
    async16(Ag1 + ka, As + s1 * 8);
    async16(Bg0 + kt, Bs + s0 * 8);
    async16(Bg1 + kt, Bs + s1 * 8);
    __syncthreads();
    bf16x8 af[4], bfr[4];
#pragma unroll
    for (int tm = 0; tm < 4; ++tm) {
      int r = wm + tm * 16 + l15;
      int cs = quad ^ ((r >> 1) & 3);
      af[tm] = *(const bf16x8*)(As + (r * 4 + cs) * 8);
    }
#pragma unroll
    for (int tn = 0; tn < 4; ++tn) {
      int r = wn + tn * 16 + l15;
      int cs = quad ^ ((r >> 1) & 3);
      bfr[tn] = *(const bf16x8*)(Bs + (r * 4 + cs) * 8);
    }
#pragma unroll
    for (int tm = 0; tm < 4; ++tm)
#pragma unroll
      for (int tn = 0; tn < 4; ++tn)
        acc[tm][tn] = __builtin_amdgcn_mfma_f32_16x16x32_bf16(af[tm], bfr[tn],
                                                              acc[tm][tn], 0, 0, 0);
    __syncthreads();
  }

#pragma unroll
  for (int tm = 0; tm < 4; ++tm)
#pragma unroll
    for (int tn = 0; tn < 4; ++tn) {
      int col = n0 + wn + tn * 16 + l15;
#pragma unroll
      for (int r = 0; r < 4; ++r) {
        int row = m0 + wm + tm * 16 + quad * 4 + r;
        outf[(size_t)row * 1024 + col] = acc[tm][tn][r];
      }
    }
}

// ---------- flash attention, in-register P, x32 QK^T, x16 PV ----------
// 1D grid 2048, swizzled: xcd = id%8; consecutive id/8 walk q-blocks of one bh.
__global__ __launch_bounds__(256, 3)
void attn_kernel(const f16* __restrict__ qbuf, const f16* __restrict__ kbuf,
                 const f16* __restrict__ vtbuf, ushort* __restrict__ aout) {
  __shared__ f16 Ks[128 * 64];   // [krow][64d], 16B chunk c swizzled: c^(row&7)
  __shared__ f16 Vs[64 * 128];   // V^T [d][128k], 16B chunk c swizzled: c^(row&15)

  const int id = blockIdx.x;
  const int xcd = id & 7, j = id >> 3;
  const int bh = xcd * 32 + (j >> 3);
  const int q0 = (j & 7) * 128;
  const f16* Qg = qbuf + (size_t)bh * 1024 * 64;
  const f16* Kg = kbuf + (size_t)bh * 1024 * 64;
  const f16* Vg = vtbuf + (size_t)bh * 64 * 1024;
  const int tid = threadIdx.x;
  const int w = tid >> 6, lane = tid & 63, quad = lane >> 4, l15 = lane & 15;
  const f32x4 fzero = {0.f, 0.f, 0.f, 0.f};

  // Q B-fragments (x32 layout): B[n=q=l15][k = dc*32 + quad*8 + i], b128 loads
  f16x8 qf[2][2];
#pragma unroll
  for (int qs = 0; qs < 2; ++qs)
#pragma unroll
    for (int dc = 0; dc < 2; ++dc)
      qf[qs][dc] = *(const f16x8*)(Qg + (size_t)(q0 + w * 32 + qs * 16 + l15) * 64 +
                                   dc * 32 + quad * 8);

  f32x4 oacc[2][4];
#pragma unroll
  for (int qs = 0; qs < 2; ++qs)
#pragma unroll
    for (int ds = 0; ds < 4; ++ds) oacc[qs][ds] = fzero;
  float mrun[2] = {-1e30f, -1e30f}, lrun[2] = {0.f, 0.f};

  for (int kt = 0; kt < 1024; kt += 128) {
#pragma unroll
    for (int i = 0; i < 4; ++i) {       // K tile
      int u = i * 256 + tid, r = u >> 3, c = u & 7;
      async16(Kg + (size_t)(kt + r) * 64 + (c ^ (r & 7)) * 8, Ks + u * 8);
    }
#pragma unroll
    for (int i = 0; i < 4; ++i) {       // V^T tile
      int u = i * 256 + tid, r = u >> 4, c = u & 15;
      async16(Vg + (size_t)r * 1024 + kt + (c ^ (r & 15)) * 8, Vs + u * 8);
    }
    __syncthreads();

    // S^T = K Q^T via 16x16x32: D[kv=quad*4+r][q=l15]
    f32x4 sacc[2][8];
#pragma unroll
    for (int qs = 0; qs < 2; ++qs)
#pragma unroll
      for (int ks = 0; ks < 8; ++ks) sacc[qs][ks] = fzero;
#pragma unroll
    for (int ks = 0; ks < 8; ++ks) {
#pragma unroll
      for (int dc = 0; dc < 2; ++dc) {
        int row = ks * 16 + l15;
        int ch = (dc * 4 + quad) ^ (row & 7);
        f16x8 kf = *(const f16x8*)(Ks + row * 64 + ch * 8);
        sacc[0][ks] = __builtin_amdgcn_mfma_f32_16x16x32_f16(kf, qf[0][dc], sacc[0][ks], 0, 0, 0);
        sacc[1][ks] = __builtin_amdgcn_mfma_f32_16x16x32_f16(kf, qf[1][dc], sacc[1][ks], 0, 0, 0);
      }
    }

    // online softmax fully in registers (lane owns q=l15; cross-quad shfl only)
    f16x4 pf[2][8];
#pragma unroll
    for (int qs = 0; qs < 2; ++qs) {
      const float* sv = (const float*)&sacc[qs][0];
      float mx = fmaxf(sv[0], sv[1]);
#pragma unroll
      for (int k = 2; k < 32; k += 2)      // v_max3 pairs
        mx = fmaxf(fmaxf(mx, sv[k]), sv[k + 1]);
      mx = fmaxf(mx, __shfl_xor(mx, 16, 64));
      mx = fmaxf(mx, __shfl_xor(mx, 32, 64));
      float mnew = fmaxf(mrun[qs], mx);
      float alpha = exp2f(mrun[qs] - mnew);
      mrun[qs] = mnew;
      float rs = 0.f;
#pragma unroll
      for (int ks = 0; ks < 8; ++ks) {
        float p0 = exp2f(sacc[qs][ks][0] - mnew);
        float p1 = exp2f(sacc[qs][ks][1] - mnew);
        float p2 = exp2f(sacc[qs][ks][2] - mnew);
        float p3 = exp2f(sacc[qs][ks][3] - mnew);
        rs += (p0 + p1) + (p2 + p3);
        union { f16x4 v; f16x2 h[2]; } pu;
        pu.h[0] = cvt_pkrtz(p0, p1);
        pu.h[1] = cvt_pkrtz(p2, p3);
        pf[qs][ks] = pu.v;
      }
      rs += __shfl_xor(rs, 16, 64);
      rs += __shfl_xor(rs, 32, 64);
      lrun[qs] = lrun[qs] * alpha + rs;
      float ar[4];
#pragma unroll
      for (int r = 0; r < 4; ++r) ar[r] = __shfl(alpha, quad * 4 + r, 64);
#pragma unroll
      for (int ds = 0; ds < 4; ++ds)
#pragma unroll
        for (int r = 0; r < 4; ++r) oacc[qs][ds][r] *= ar[r];
    }

    // O += P V : P already in x16 A layout; V^T B-frag from LDS
#pragma unroll
    for (int ks = 0; ks < 8; ++ks) {
#pragma unroll
      for (int ds = 0; ds < 4; ++ds) {
        int row = ds * 16 + l15;
        int c16 = ks * 2 + (quad >> 1);
        f16x4 vf = *(const f16x4*)(Vs + row * 128 + ((c16 ^ (row & 15)) * 8) + (quad & 1) * 4);
        oacc[0][ds] = __builtin_amdgcn_mfma_f32_16x16x16f16(pf[0][ks], vf, oacc[0][ds], 0, 0, 0);
        oacc[1][ds] = __builtin_amdgcn_mfma_f32_16x16x16f16(pf[1][ks], vf, oacc[1][ds], 0, 0, 0);
      }
    }
    __syncthreads();
  }

  // epilogue: O /= l -> bf16 via wave-private LDS transpose -> 1KB stores
  // head-major out: aout[(bh*1024 + n)*64 + d]
  ushort* eps = (ushort*)Ks + w * 2048;   // 4KB per wave
#pragma unroll
  for (int qs = 0; qs < 2; ++qs) {
    float linv[4];
#pragma unroll
    for (int r = 0; r < 4; ++r) linv[r] = 1.f / __shfl(lrun[qs], quad * 4 + r, 64);
#pragma unroll
    for (int ds = 0; ds < 4; ++ds)
#pragma unroll
      for (int r = 0; r < 4; ++r) {
        int row_loc = qs * 16 + quad * 4 + r;
        int col = ds * 16 + l15;
        int ch = (col >> 3) ^ (row_loc & 7);
        eps[row_loc * 64 + ch * 8 + (col & 7)] = f2bf(oacc[qs][ds][r] * linv[r]);
      }
  }
  __syncthreads();
  const size_t obase = ((size_t)bh * 1024 + q0 + w * 32) * 64;
#pragma unroll
  for (int i = 0; i < 4; ++i) {
    int row_loc = i * 8 + (lane >> 3);
    int ch = lane & 7;
    uint4 v = *(const uint4*)(eps + row_loc * 64 + ((ch ^ (row_loc & 7)) * 8));
    *(uint4*)(aout + obase + row_loc * 64 + ch * 8) = v;
  }
}

// ---------- launch ----------
extern "C" void kernel_launch(void* const* d_in, const int* in_sizes, int n_in,
                              void* d_out, int out_size, void* d_ws, size_t ws_size,
                              hipStream_t stream) {
  const float* x    = (const float*)d_in[0];
  const float* t    = (const float*)d_in[1];
  const float* nw   = (const float*)d_in[2];
  const float* mw   = (const float*)d_in[3];
  const float* qkvw = (const float*)d_in[4];
  const float* wow  = (const float*)d_in[5];
  float* out = (float*)d_out;
  char* ws = (char*)d_ws;

  float*  modbuf  = (float*)(ws);                    // 131072 B
  ushort* hbuf    = (ushort*)(ws + 131072);          // 32 MB (bf16)
  ushort* wqk_b   = (ushort*)(ws + 33685504);        // 4 MB
  ushort* wv_b    = (ushort*)(ws + 37879808);        // 2 MB
  ushort* wow_b   = (ushort*)(ws + 39976960);        // 2 MB
  f16*    qbuf    = (f16*)(ws + 42074112);           // 32 MB (rope+scale applied)
  f16*    kbuf    = (f16*)(ws + 75628544);           // 32 MB (rope applied)
  f16*    vtbuf   = (f16*)(ws + 109182976);          // 32 MB (V^T [b][f][n])
  ushort* abuf    = (ushort*)(ws + 142737408);       // 32 MB (bf16, head-major)

  prep_kernel<<<dim3(6144), dim3(256), 0, stream>>>(
      t, mw, modbuf, qkvw, wqk_b, wv_b, wow, wow_b);
  rms_mod_kernel<<<dim3(16384), dim3(256), 0, stream>>>(x, nw, modbuf, hbuf);
  gemm_qkv_kernel<<<dim3(768), dim3(512), 0, stream>>>(
      hbuf, wqk_b, wv_b, qbuf, kbuf, vtbuf);
  attn_kernel<<<dim3(2048), dim3(256), 0, stream>>>(qbuf, kbuf, vtbuf, abuf);
  gemm_wo_kernel<<<dim3(8, 128), dim3(256), 0, stream>>>(abuf, wow_b, out);
}

// Round 2
// 406.030 us; speedup vs baseline: 1.1203x; 1.0772x over previous
//
#include <hip/hip_runtime.h>
#include <stdint.h>

// ---------- types ----------
typedef __bf16    bf16x8 __attribute__((ext_vector_type(8)));
typedef float     f32x4  __attribute__((ext_vector_type(4)));
typedef _Float16  f16;
typedef _Float16  f16x2  __attribute__((ext_vector_type(2)));
typedef _Float16  f16x4  __attribute__((ext_vector_type(4)));
typedef _Float16  f16x8  __attribute__((ext_vector_type(8)));

#define DEV __device__ __forceinline__

DEV ushort f2bf(float f) {               // RTNE float -> bf16 bits
  union { float f; uint32_t u; } v; v.f = f;
  uint32_t u = v.u;
  return (ushort)((u + 0x7fffu + ((u >> 16) & 1u)) >> 16);
}

DEV f16x2 cvt_pkrtz(float a, float b) {  // v_cvt_pkrtz_f16_f32, bit-cast to f16x2
  return __builtin_bit_cast(f16x2, __builtin_amdgcn_cvt_pkrtz(a, b));
}

// async global->LDS, 16B per lane. LDS dest must be wave-uniform base + lane*16.
DEV void async16(const void* g, void* l) {
  __builtin_amdgcn_global_load_lds(
      (__attribute__((address_space(1))) void*)(uintptr_t)g,
      (__attribute__((address_space(3))) void*)(uint32_t)(uintptr_t)l,
      16, 0, 0);
}

// ---------- prep kernel: mod-gemm + weight split/cast + wo cast (one launch) ----
__global__ __launch_bounds__(256)
void prep_kernel(const float* __restrict__ t, const float* __restrict__ mw,
                 float* __restrict__ mod,
                 const float* __restrict__ qkvw, ushort* __restrict__ wqk,
                 ushort* __restrict__ wv,
                 const float* __restrict__ wow, ushort* __restrict__ wowb) {
  const int id = blockIdx.x;
  const int tid = threadIdx.x;
  if (id < 2048) {
    // mod = t @ mod_w.T : column j, wave w handles batches w*4..w*4+3
    const int j = id;
    const int w = tid >> 6, lane = tid & 63;
    float wr[16];
#pragma unroll
    for (int i = 0; i < 16; ++i) wr[i] = mw[(size_t)j * 1024 + lane + i * 64];
#pragma unroll
    for (int bb = 0; bb < 4; ++bb) {
      int b = w * 4 + bb;
      float s = 0.f;
#pragma unroll
      for (int i = 0; i < 16; ++i) s += wr[i] * t[b * 1024 + lane + i * 64];
#pragma unroll
      for (int m = 32; m >= 1; m >>= 1) s += __shfl_xor(s, m, 64);
      if (lane == 0) mod[b * 2048 + j] = s;
    }
  } else if (id < 5120) {
    // split qkv_w row j -> wqk (q,k interleaved per head) or wv
    const int j = id - 2048;
    uint32_t hd = (uint32_t)j / 192u;
    uint32_t rem = (uint32_t)j - hd * 192u;
    ushort* dst = (rem < 128u) ? (wqk + (size_t)(hd * 128u + rem) * 1024)
                               : (wv + (size_t)(hd * 64u + (rem - 128u)) * 1024);
    float4 v = ((const float4*)(qkvw + (size_t)j * 1024))[tid];
    ushort4 o;
    o.x = f2bf(v.x); o.y = f2bf(v.y); o.z = f2bf(v.z); o.w = f2bf(v.w);
    ((ushort4*)dst)[tid] = o;
  } else {
    // wo cast: 1024 blocks x 256 thr x float4
    const int i = (id - 5120) * 256 + tid;   // < 262144
    float4 v = ((const float4*)wow)[i];
    ushort4 o;
    o.x = f2bf(v.x); o.y = f2bf(v.y); o.z = f2bf(v.z); o.w = f2bf(v.w);
    ((ushort4*)wowb)[i] = o;
  }
}

// ---------- RMSNorm + modulate -> bf16 h ----------
__global__ __launch_bounds__(256)
void rms_mod_kernel(const float* __restrict__ x, const float* __restrict__ nw,
                    const float* __restrict__ mod, ushort* __restrict__ h) {
  int row = blockIdx.x;
  int b = row >> 10;
  int tid = threadIdx.x;
  const float4 xv = *(const float4*)(x + (size_t)row * 1024 + tid * 4);
  float ss = xv.x * xv.x + xv.y * xv.y + xv.z * xv.z + xv.w * xv.w;
#pragma unroll
  for (int m = 32; m >= 1; m >>= 1) ss += __shfl_xor(ss, m, 64);
  __shared__ float red[4];
  int w = tid >> 6, lane = tid & 63;
  if (lane == 0) red[w] = ss;
  __syncthreads();
  float tot = red[0] + red[1] + red[2] + red[3];
  float rn = rsqrtf(tot * (1.f / 1024.f) + 1e-6f);
  float4 wv = *(const float4*)(nw + tid * 4);
  float4 sc = *(const float4*)(mod + (size_t)b * 2048 + tid * 4);
  float4 sh = *(const float4*)(mod + (size_t)b * 2048 + 1024 + tid * 4);
  ushort4 o;
  o.x = f2bf(xv.x * rn * wv.x * (1.f + sc.x) + sh.x);
  o.y = f2bf(xv.y * rn * wv.y * (1.f + sc.y) + sh.y);
  o.z = f2bf(xv.z * rn * wv.z * (1.f + sc.z) + sh.z);
  o.w = f2bf(xv.w * rn * wv.w * (1.f + sc.w) + sh.w);
  *(ushort4*)(h + (size_t)row * 1024 + tid * 4) = o;
}

// ---------- QKV GEMM v2: 256x256 tile, BK=64, 8 waves, 4-phase deep pipeline ----
// mode1 = q/k proj + fused RoPE, mode2 = V^T.  C[M][N] = A[M][K] * B[N][K]^T.
__global__ __launch_bounds__(512, 2)
void gemm_qkv_kernel(const ushort* __restrict__ hbuf, const ushort* __restrict__ wqk,
                     const ushort* __restrict__ wvw,
                     f16* __restrict__ qb, f16* __restrict__ kb,
                     f16* __restrict__ vtb) {
  __shared__ ushort smem[65536];          // 128 KB
  const int id0 = blockIdx.x;
  const int id = (id0 & 7) * 96 + (id0 >> 3);   // XCD swizzle (768 % 8 == 0)
  int mode, m0, n0;
  const ushort *A, *B;
  if (id < 512) {                         // q/k: M=16384 tokens, N=2048 qk-rows
    mode = 1; m0 = (id >> 3) * 256; n0 = (id & 7) * 256; A = hbuf; B = wqk;
  } else {                                // V^T: M=1024 features, N=16384 tokens
    const int i2 = id - 512;
    mode = 2; n0 = (i2 >> 2) * 256; m0 = (i2 & 3) * 256; A = wvw; B = hbuf;
  }
  const int tid = threadIdx.x;
  const int w = tid >> 6, lane = tid & 63, quad = lane >> 4, l15 = lane & 15;
  const int wm = w >> 2, wn = w & 3;      // 2 x 4 wave grid; per-wave C: 128x64

  const int srow = tid >> 3;
  const int sch  = (tid & 7) ^ (srow & 7);
  const int soff = srow * 1024 + sch * 8;           // elems into operand panel
  const ushort* const Abase = A + (size_t)m0 * 1024;
  const ushort* const Bbase = B + (size_t)n0 * 1024;
  ushort* const As0 = smem;                         // 2 x 16384 ushort
  ushort* const Bs0 = smem + 32768;                 // 2 x 16384 ushort
  const int sdst = tid * 8;                         // ushort offset, lane*16B

#define STG_A(d, t, h) do { \
    async16(Abase + (h) * 131072 + soff + (t) * 64,          As0 + (d) * 16384 + (h) * 8192 + sdst); \
    async16(Abase + (h) * 131072 + 65536 + soff + (t) * 64,  As0 + (d) * 16384 + (h) * 8192 + 4096 + sdst); } while (0)
#define STG_B(d, t, h) do { \
    async16(Bbase + (h) * 131072 + soff + (t) * 64,          Bs0 + (d) * 16384 + (h) * 8192 + sdst); \
    async16(Bbase + (h) * 131072 + 65536 + soff + (t) * 64,  Bs0 + (d) * 16384 + (h) * 8192 + 4096 + sdst); } while (0)

  int aoff[2], boff[2];
#pragma unroll
  for (int kk = 0; kk < 2; ++kk) {
    const int swz = (((kk * 4 + quad) ^ (l15 & 7)) * 8);
    aoff[kk] = (wm * 128 + l15) * 64 + swz;
    boff[kk] = (wn * 64 + l15) * 64 + swz;
  }

  const f32x4 fzero = {0.f, 0.f, 0.f, 0.f};
  f32x4 acc[8][4];
#pragma unroll
  for (int a = 0; a < 8; ++a)
#pragma unroll
    for (int b = 0; b < 4; ++b) acc[a][b] = fzero;

  STG_A(0, 0, 0); STG_A(0, 0, 1); STG_B(0, 0, 0); STG_B(0, 0, 1);
  asm volatile("s_waitcnt vmcnt(0)" ::: "memory");
  __builtin_amdgcn_s_barrier();

  bf16x8 af[4][2];
  bf16x8 bfv[2][2];
#pragma unroll 2
  for (int t = 0; t < 16; ++t) {
    const int cur = t & 1, nxt = cur ^ 1;
    const int tn = (t < 15) ? t + 1 : 15;
    const ushort* Asc = As0 + cur * 16384;
    const ushort* Bsc = Bs0 + cur * 16384;

    // ---- phase 0 ----
#pragma unroll
    for (int mf = 0; mf < 4; ++mf)
#pragma unroll
      for (int kk = 0; kk < 2; ++kk)
        af[mf][kk] = *(const bf16x8*)(Asc + mf * 1024 + aoff[kk]);
#pragma unroll
    for (int nf = 0; nf < 2; ++nf)
#pragma unroll
      for (int kk = 0; kk < 2; ++kk)
        bfv[nf][kk] = *(const bf16x8*)(Bsc + nf * 1024 + boff[kk]);
    STG_A(nxt, tn, 0);
    __builtin_amdgcn_s_barrier();
    __builtin_amdgcn_s_setprio(1);
#pragma unroll
    for (int mf = 0; mf < 4; ++mf)
#pragma unroll
      for (int nf = 0; nf < 2; ++nf)
#pragma unroll
        for (int kk = 0; kk < 2; ++kk)
          acc[mf][nf] = __builtin_amdgcn_mfma_f32_16x16x32_bf16(
              af[mf][kk], bfv[nf][kk], acc[mf][nf], 0, 0, 0);
    __builtin_amdgcn_s_setprio(0);
    __builtin_amdgcn_s_barrier();

    // ---- phase 1 ----
#pragma unroll
    for (int mf = 0; mf < 4; ++mf)
#pragma unroll
      for (int kk = 0; kk < 2; ++kk)
        af[mf][kk] = *(const bf16x8*)(Asc + (4 + mf) * 1024 + aoff[kk]);
    STG_A(nxt, tn, 1);
    __builtin_amdgcn_s_barrier();
    __builtin_amdgcn_s_setprio(1);
#pragma unroll
    for (int mf = 0; mf < 4; ++mf)
#pragma unroll
      for (int nf = 0; nf < 2; ++nf)
#pragma unroll
        for (int kk = 0; kk < 2; ++kk)
          acc[4 + mf][nf] = __builtin_amdgcn_mfma_f32_16x16x32_bf16(
              af[mf][kk], bfv[nf][kk], acc[4 + mf][nf], 0, 0, 0);
    __builtin_amdgcn_s_setprio(0);
    __builtin_amdgcn_s_barrier();

    // ---- phase 2 ----
#pragma unroll
    for (int nf = 0; nf < 2; ++nf)
#pragma unroll
      for (int kk = 0; kk < 2; ++kk)
        bfv[nf][kk] = *(const bf16x8*)(Bsc + (2 + nf) * 1024 + boff[kk]);
    STG_B(nxt, tn, 0);
    __builtin_amdgcn_s_barrier();
    __builtin_amdgcn_s_setprio(1);
#pragma unroll
    for (int mf = 0; mf < 4; ++mf)
#pragma unroll
      for (int nf = 0; nf < 2; ++nf)
#pragma unroll
        for (int kk = 0; kk < 2; ++kk)
          acc[4 + mf][2 + nf] = __builtin_amdgcn_mfma_f32_16x16x32_bf16(
              af[mf][kk], bfv[nf][kk], acc[4 + mf][2 + nf], 0, 0, 0);
    __builtin_amdgcn_s_setprio(0);
    __builtin_amdgcn_s_barrier();

    // ---- phase 3 ----
#pragma unroll
    for (int mf = 0; mf < 4; ++mf)
#pragma unroll
      for (int kk = 0; kk < 2; ++kk)
        af[mf][kk] = *(const bf16x8*)(Asc + mf * 1024 + aoff[kk]);
    STG_B(nxt, tn, 1);
    __builtin_amdgcn_s_barrier();
    __builtin_amdgcn_s_setprio(1);
#pragma unroll
    for (int mf = 0; mf < 4; ++mf)
#pragma unroll
      for (int nf = 0; nf < 2; ++nf)
#pragma unroll
        for (int kk = 0; kk < 2; ++kk)
          acc[mf][2 + nf] = __builtin_amdgcn_mfma_f32_16x16x32_bf16(
              af[mf][kk], bfv[nf][kk], acc[mf][2 + nf], 0, 0, 0);
    __builtin_amdgcn_s_setprio(0);
    asm volatile("s_waitcnt vmcnt(0)" ::: "memory");
    __builtin_amdgcn_s_barrier();
  }
#undef STG_A
#undef STG_B

  // ---- epilogue: wave-private LDS transpose (128x64) -> full-line stores ----
  ushort* eps = smem + w * 8192;          // 16 KB per wave
#pragma unroll
  for (int mf = 0; mf < 8; ++mf)
#pragma unroll
    for (int nf = 0; nf < 4; ++nf)
#pragma unroll
      for (int r = 0; r < 4; ++r) {
        const int row_loc = mf * 16 + quad * 4 + r;
        const int col = nf * 16 + l15;
        const int ch = (col >> 3) ^ (row_loc & 7);
        union { f16 h; ushort u; } cv;
        cv.h = (f16)acc[mf][nf][r];
        eps[row_loc * 64 + ch * 8 + (col & 7)] = cv.u;
      }

  const int ch = lane & 7;
  const int rbase = lane >> 3;
  const int gcol = n0 + wn * 64;
  if (mode == 1) {
    const int hd = gcol >> 7, part = (gcol >> 6) & 1;
    const float QS = part ? 1.f : 0.125f * 1.44269504f;   // q: scale*log2e fold
    f16* const outp = part ? kb : qb;
    float th[4];
#pragma unroll
    for (int t2 = 0; t2 < 4; ++t2)
      th[t2] = __expf(-(float)((ch * 4 + t2) & 15) * 0.5756462732485114f); // ln(1e4)/16
#pragma unroll
    for (int i = 0; i < 16; ++i) {
      const int row_loc = i * 8 + rbase;
      union { uint4 u4; f16 h[8]; } uv;
      uv.u4 = *(const uint4*)(eps + row_loc * 64 + ((ch ^ (row_loc & 7)) * 8));
      const int m = m0 + wm * 128 + row_loc;   // token index
      const int n = m & 1023;
      const float xpos = (float)(n & 31), ypos = (float)(n >> 5);
#pragma unroll
      for (int t2 = 0; t2 < 4; ++t2) {
        const int p = ch * 4 + t2;
        const float pos = (p < 16) ? xpos : ypos;
        float sn, cs;
        __sincosf(pos * th[t2], &sn, &cs);
        const float x0 = (float)uv.h[2 * t2], x1 = (float)uv.h[2 * t2 + 1];
        f16x2 ro = cvt_pkrtz((x0 * cs - x1 * sn) * QS, (x1 * cs + x0 * sn) * QS);
        uv.h[2 * t2] = ro[0];
        uv.h[2 * t2 + 1] = ro[1];
      }
      f16* dst = outp + (((size_t)((m >> 10) * 16 + hd) * 1024 + n) * 64 + ch * 8);
      *(uint4*)dst = uv.u4;
    }
  } else {
    // V^T store with 8B-half swap on rows with bit3 set (attn V bank-conflict
    // fix: LDS read uses half-bit (quad&1)^((row>>3)&1); swap here compensates).
    // (m>>3)&1 == i&1: compile-time per iteration.
    const int b = gcol >> 10, tb = gcol & 1023;
#pragma unroll
    for (int i = 0; i < 16; ++i) {
      const int row_loc = i * 8 + rbase;
      uint4 v = *(const uint4*)(eps + row_loc * 64 + ((ch ^ (row_loc & 7)) * 8));
      if (i & 1) { unsigned t0 = v.x, t1 = v.y; v.x = v.z; v.y = v.w; v.z = t0; v.w = t1; }
      const int m = m0 + wm * 128 + row_loc;   // feature row
      f16* dst = vtb + ((size_t)(b * 1024 + m) * 1024 + tb + ch * 8);
      *(uint4*)dst = v;
    }
  }
}

// ---------- WO GEMM: out[16384][1024] fp32 = abuf(head-major) @ wow^T ----------
__global__ __launch_bounds__(256, 3)
void gemm_wo_kernel(const ushort* __restrict__ A, const ushort* __restrict__ B,
                    float* __restrict__ outf) {
  __shared__ ushort smem[8192];
  ushort* As = smem;
  ushort* Bs = smem + 4096;
  const int K = 1024;
  const int m0 = blockIdx.y * 128, n0 = blockIdx.x * 128;
  const int tid = threadIdx.x;
  const int w = tid >> 6, lane = tid & 63, quad = lane >> 4, l15 = lane & 15;
  const int wm = (w >> 1) * 64, wn = (w & 1) * 64;
  const f32x4 fzero = {0.f, 0.f, 0.f, 0.f};
  f32x4 acc[4][4];
#pragma unroll
  for (int a = 0; a < 4; ++a)
#pragma unroll
    for (int b = 0; b < 4; ++b) acc[a][b] = fzero;

  const int s0 = tid, s1 = 256 + tid;
  const int r0 = s0 >> 2, c0 = (s0 & 3) ^ ((r0 >> 1) & 3);
  const int r1 = s1 >> 2, c1 = (s1 & 3) ^ ((r1 >> 1) & 3);
  const int b0 = m0 >> 10, nb = m0 & 1023;
  const size_t Abase = (size_t)b0 * 16 * 1024 * 64;
  const ushort* Ag0 = A + Abase + (size_t)(nb + r0) * 64 + c0 * 8;
  const ushort* Ag1 = A + Abase + (size_t)(nb + r1) * 64 + c1 * 8;
  const ushort* Bg0 = B + (size_t)(n0 + r0) * K + c0 * 8;
  const ushort* Bg1 = B + (size_t)(n0 + r1) * K + c1 * 8;

  for (int kt = 0; kt < K; kt += 32) {
    const size_t ka = (size_t)(kt >> 6) * 65536 + (size_t)(kt & 63);
    async16(Ag0 + ka, As + s0 * 8);
    async16(Ag1 + ka, As + s1 * 8);
    async16(Bg0 + kt, Bs + s0 * 8);
    async16(Bg1 + kt, Bs + s1 * 8);
    __syncthreads();
    bf16x8 af[4], bfr[4];
#pragma unroll
    for (int tm = 0; tm < 4; ++tm) {
      int r = wm + tm * 16 + l15;
      int cs = quad ^ ((r >> 1) & 3);
      af[tm] = *(const bf16x8*)(As + (r * 4 + cs) * 8);
    }
#pragma unroll
    for (int tn = 0; tn < 4; ++tn) {
      int r = wn + tn * 16 + l15;
      int cs = quad ^ ((r >> 1) & 3);
      bfr[tn] = *(const bf16x8*)(Bs + (r * 4 + cs) * 8);
    }
#pragma unroll
    for (int tm = 0; tm < 4; ++tm)
#pragma unroll
      for (int tn = 0; tn < 4; ++tn)
        acc[tm][tn] = __builtin_amdgcn_mfma_f32_16x16x32_bf16(af[tm], bfr[tn],
                                                              acc[tm][tn], 0, 0, 0);
    __syncthreads();
  }

#pragma unroll
  for (int tm = 0; tm < 4; ++tm)
#pragma unroll
    for (int tn = 0; tn < 4; ++tn) {
      int col = n0 + wn + tn * 16 + l15;
#pragma unroll
      for (int r = 0; r < 4; ++r) {
        int row = m0 + wm + tm * 16 + quad * 4 + r;
        outf[(size_t)row * 1024 + col] = acc[tm][tn][r];
      }
    }
}

// ---------- flash attention v2: dbuf K/V, native exp2, defer-max, V-bank fix ----
__global__ __launch_bounds__(256, 2)
void attn_kernel(const f16* __restrict__ qbuf, const f16* __restrict__ kbuf,
                 const f16* __restrict__ vtbuf, ushort* __restrict__ aout) {
  __shared__ f16 Ks[2][128 * 64];   // [buf][krow][64d], chunk c ^ (row&7)
  __shared__ f16 Vs[2][64 * 128];   // [buf] V^T [d][128k], chunk c ^ (row&15),
                                    //   8B-half pre-swapped in global for row bit3

  const int id = blockIdx.x;
  const int xcd = id & 7, j = id >> 3;
  const int bh = xcd * 32 + (j >> 3);
  const int q0 = (j & 7) * 128;
  const f16* Qg = qbuf + (size_t)bh * 1024 * 64;
  const f16* Kg = kbuf + (size_t)bh * 1024 * 64;
  const f16* Vg = vtbuf + (size_t)bh * 64 * 1024;
  const int tid = threadIdx.x;
  const int w = tid >> 6, lane = tid & 63, quad = lane >> 4, l15 = lane & 15;
  const f32x4 fzero = {0.f, 0.f, 0.f, 0.f};

  // Q B-fragments (x32 layout): B[n=q=l15][k = dc*32 + quad*8 + i]
  f16x8 qf[2][2];
#pragma unroll
  for (int qs = 0; qs < 2; ++qs)
#pragma unroll
    for (int dc = 0; dc < 2; ++dc)
      qf[qs][dc] = *(const f16x8*)(Qg + (size_t)(q0 + w * 32 + qs * 16 + l15) * 64 +
                                   dc * 32 + quad * 8);

  f32x4 oacc[2][4];
#pragma unroll
  for (int qs = 0; qs < 2; ++qs)
#pragma unroll
    for (int ds = 0; ds < 4; ++ds) oacc[qs][ds] = fzero;
  float mrun[2] = {-1e30f, -1e30f}, lrun[2] = {0.f, 0.f};

  // prologue: stage tile 0
#pragma unroll
  for (int i = 0; i < 4; ++i) {
    int u = i * 256 + tid, r = u >> 3, c = u & 7;
    async16(Kg + (size_t)r * 64 + (c ^ (r & 7)) * 8, &Ks[0][u * 8]);
  }
#pragma unroll
  for (int i = 0; i < 4; ++i) {
    int u = i * 256 + tid, r = u >> 4, c = u & 15;
    async16(Vg + (size_t)r * 1024 + (c ^ (r & 15)) * 8, &Vs[0][u * 8]);
  }
  __syncthreads();

#pragma unroll 2
  for (int kt = 0; kt < 1024; kt += 128) {
    const int cur = (kt >> 7) & 1;
    // prefetch next tile into other buffer (issue early, drain at iter end)
    if (kt + 128 < 1024) {
      const int nkt = kt + 128;
#pragma unroll
      for (int i = 0; i < 4; ++i) {
        int u = i * 256 + tid, r = u >> 3, c = u & 7;
        async16(Kg + (size_t)(nkt + r) * 64 + (c ^ (r & 7)) * 8, &Ks[cur ^ 1][u * 8]);
      }
#pragma unroll
      for (int i = 0; i < 4; ++i) {
        int u = i * 256 + tid, r = u >> 4, c = u & 15;
        async16(Vg + (size_t)r * 1024 + nkt + (c ^ (r & 15)) * 8, &Vs[cur ^ 1][u * 8]);
      }
    }
    const f16* Ksc = Ks[cur];
    const f16* Vsc = Vs[cur];

    // S^T = K Q^T via 16x16x32: D[kv=quad*4+r][q=l15]
    f32x4 sacc[2][8];
#pragma unroll
    for (int qs = 0; qs < 2; ++qs)
#pragma unroll
      for (int ks = 0; ks < 8; ++ks) sacc[qs][ks] = fzero;
#pragma unroll
    for (int ks = 0; ks < 8; ++ks) {
#pragma unroll
      for (int dc = 0; dc < 2; ++dc) {
        int row = ks * 16 + l15;
        int ch = (dc * 4 + quad) ^ (row & 7);
        f16x8 kf = *(const f16x8*)(Ksc + row * 64 + ch * 8);
        sacc[0][ks] = __builtin_amdgcn_mfma_f32_16x16x32_f16(kf, qf[0][dc], sacc[0][ks], 0, 0, 0);
        sacc[1][ks] = __builtin_amdgcn_mfma_f32_16x16x32_f16(kf, qf[1][dc], sacc[1][ks], 0, 0, 0);
      }
    }

    // online softmax, defer-max (THR=8 in log2 units), native v_exp_f32
    f16x4 pf[2][8];
#pragma unroll
    for (int qs = 0; qs < 2; ++qs) {
      const float* sv = (const float*)&sacc[qs][0];
      float mx = fmaxf(sv[0], sv[1]);
#pragma unroll
      for (int k = 2; k < 32; k += 2)      // v_max3 pairs
        mx = fmaxf(fmaxf(mx, sv[k]), sv[k + 1]);
      mx = fmaxf(mx, __shfl_xor(mx, 16, 64));
      mx = fmaxf(mx, __shfl_xor(mx, 32, 64));
      if (__any(mx - mrun[qs] > 8.f)) {    // rare: rescale path
        float mnew = fmaxf(mrun[qs], mx);
        float alpha = __builtin_amdgcn_exp2f(mrun[qs] - mnew);
        mrun[qs] = mnew;
        lrun[qs] *= alpha;
        float ar[4];
#pragma unroll
        for (int r = 0; r < 4; ++r) ar[r] = __shfl(alpha, quad * 4 + r, 64);
#pragma unroll
        for (int ds = 0; ds < 4; ++ds)
#pragma unroll
          for (int r = 0; r < 4; ++r) oacc[qs][ds][r] *= ar[r];
      }
      const float mnew = mrun[qs];
      float rs = 0.f;
#pragma unroll
      for (int ks = 0; ks < 8; ++ks) {
        float p0 = __builtin_amdgcn_exp2f(sacc[qs][ks][0] - mnew);
        float p1 = __builtin_amdgcn_exp2f(sacc[qs][ks][1] - mnew);
        float p2 = __builtin_amdgcn_exp2f(sacc[qs][ks][2] - mnew);
        float p3 = __builtin_amdgcn_exp2f(sacc[qs][ks][3] - mnew);
        rs += (p0 + p1) + (p2 + p3);
        union { f16x4 v; f16x2 h[2]; } pu;
        pu.h[0] = cvt_pkrtz(p0, p1);
        pu.h[1] = cvt_pkrtz(p2, p3);
        pf[qs][ks] = pu.v;
      }
      rs += __shfl_xor(rs, 16, 64);
      rs += __shfl_xor(rs, 32, 64);
      lrun[qs] += rs;
    }

    // O += P V : P in x16 A layout; V^T B-frag from LDS (conflict-free banks:
    // half-bit = (quad&1) ^ ((row>>3)&1), matches global pre-swap)
#pragma unroll
    for (int ks = 0; ks < 8; ++ks) {
#pragma unroll
      for (int ds = 0; ds < 4; ++ds) {
        int row = ds * 16 + l15;
        int c16 = ks * 2 + (quad >> 1);
        int half = (quad & 1) ^ ((l15 >> 3) & 1);
        f16x4 vf = *(const f16x4*)(Vsc + row * 128 + ((c16 ^ (row & 15)) * 8) + half * 4);
        oacc[0][ds] = __builtin_amdgcn_mfma_f32_16x16x16f16(pf[0][ks], vf, oacc[0][ds], 0, 0, 0);
        oacc[1][ds] = __builtin_amdgcn_mfma_f32_16x16x16f16(pf[1][ks], vf, oacc[1][ds], 0, 0, 0);
      }
    }
    __syncthreads();   // drains prefetch (vmcnt0) + protects buffer swap
  }

  // epilogue: O /= l -> bf16 via wave-private LDS transpose -> 1KB stores
  ushort* eps = (ushort*)&Ks[0][0] + w * 2048;   // 4KB per wave
#pragma unroll
  for (int qs = 0; qs < 2; ++qs) {
    float linv[4];
#pragma unroll
    for (int r = 0; r < 4; ++r)
      linv[r] = __builtin_amdgcn_rcpf(__shfl(lrun[qs], quad * 4 + r, 64));
#pragma unroll
    for (int ds = 0; ds < 4; ++ds)
#pragma unroll
      for (int r = 0; r < 4; ++r) {
        int row_loc = qs * 16 + quad * 4 + r;
        int col = ds * 16 + l15;
        int ch = (col >> 3) ^ (row_loc & 7);
        eps[row_loc * 64 + ch * 8 + (col & 7)] = f2bf(oacc[qs][ds][r] * linv[r]);
      }
  }
  __syncthreads();
  const size_t obase = ((size_t)bh * 1024 + q0 + w * 32) * 64;
#pragma unroll
  for (int i = 0; i < 4; ++i) {
    int row_loc = i * 8 + (lane >> 3);
    int ch = lane & 7;
    uint4 v = *(const uint4*)(eps + row_loc * 64 + ((ch ^ (row_loc & 7)) * 8));
    *(uint4*)(aout + obase + row_loc * 64 + ch * 8) = v;
  }
}

// ---------- launch ----------
extern "C" void kernel_launch(void* const* d_in, const int* in_sizes, int n_in,
                              void* d_out, int out_size, void* d_ws, size_t ws_size,
                              hipStream_t stream) {
  const float* x    = (const float*)d_in[0];
  const float* t    = (const float*)d_in[1];
  const float* nw   = (const float*)d_in[2];
  const float* mw   = (const float*)d_in[3];
  const float* qkvw = (const float*)d_in[4];
  const float* wow  = (const float*)d_in[5];
  float* out = (float*)d_out;
  char* ws = (char*)d_ws;

  float*  modbuf  = (float*)(ws);                    // 131072 B
  ushort* hbuf    = (ushort*)(ws + 131072);          // 32 MB (bf16)
  ushort* wqk_b   = (ushort*)(ws + 33685504);        // 4 MB
  ushort* wv_b    = (ushort*)(ws + 37879808);        // 2 MB
  ushort* wow_b   = (ushort*)(ws + 39976960);        // 2 MB
  f16*    qbuf    = (f16*)(ws + 42074112);           // 32 MB (rope+scale applied)
  f16*    kbuf    = (f16*)(ws + 75628544);           // 32 MB (rope applied)
  f16*    vtbuf   = (f16*)(ws + 109182976);          // 32 MB (V^T, half-swapped rows)
  ushort* abuf    = (ushort*)(ws + 142737408);       // 32 MB (bf16, head-major)

  prep_kernel<<<dim3(6144), dim3(256), 0, stream>>>(
      t, mw, modbuf, qkvw, wqk_b, wv_b, wow, wow_b);
  rms_mod_kernel<<<dim3(16384), dim3(256), 0, stream>>>(x, nw, modbuf, hbuf);
  gemm_qkv_kernel<<<dim3(768), dim3(512), 0, stream>>>(
      hbuf, wqk_b, wv_b, qbuf, kbuf, vtbuf);
  attn_kernel<<<dim3(2048), dim3(256), 0, stream>>>(qbuf, kbuf, vtbuf, abuf);
  gemm_wo_kernel<<<dim3(8, 128), dim3(256), 0, stream>>>(abuf, wow_b, out);
}

// Round 3
// 391.366 us; speedup vs baseline: 1.1623x; 1.0375x over previous
//
#include <hip/hip_runtime.h>
#include <stdint.h>

// ---------- types ----------
typedef __bf16    bf16x8 __attribute__((ext_vector_type(8)));
typedef float     f32x4  __attribute__((ext_vector_type(4)));
typedef _Float16  f16;
typedef _Float16  f16x2  __attribute__((ext_vector_type(2)));
typedef _Float16  f16x4  __attribute__((ext_vector_type(4)));
typedef _Float16  f16x8  __attribute__((ext_vector_type(8)));

#define DEV __device__ __forceinline__

DEV ushort f2bf(float f) {               // RTNE float -> bf16 bits
  union { float f; uint32_t u; } v; v.f = f;
  uint32_t u = v.u;
  return (ushort)((u + 0x7fffu + ((u >> 16) & 1u)) >> 16);
}

DEV f16x2 cvt_pkrtz(float a, float b) {  // v_cvt_pkrtz_f16_f32, bit-cast to f16x2
  return __builtin_bit_cast(f16x2, __builtin_amdgcn_cvt_pkrtz(a, b));
}

// async global->LDS, 16B per lane. LDS dest must be wave-uniform base + lane*16.
DEV void async16(const void* g, void* l) {
  __builtin_amdgcn_global_load_lds(
      (__attribute__((address_space(1))) void*)(uintptr_t)g,
      (__attribute__((address_space(3))) void*)(uint32_t)(uintptr_t)l,
      16, 0, 0);
}

// ---------- prep kernel: mod-gemm + weight split/cast + wo cast (one launch) ----
__global__ __launch_bounds__(256)
void prep_kernel(const float* __restrict__ t, const float* __restrict__ mw,
                 float* __restrict__ mod,
                 const float* __restrict__ qkvw, ushort* __restrict__ wqk,
                 ushort* __restrict__ wv,
                 const float* __restrict__ wow, ushort* __restrict__ wowb) {
  const int id = blockIdx.x;
  const int tid = threadIdx.x;
  if (id < 2048) {
    // mod = t @ mod_w.T : column j, wave w handles batches w*4..w*4+3
    const int j = id;
    const int w = tid >> 6, lane = tid & 63;
    float wr[16];
#pragma unroll
    for (int i = 0; i < 16; ++i) wr[i] = mw[(size_t)j * 1024 + lane + i * 64];
#pragma unroll
    for (int bb = 0; bb < 4; ++bb) {
      int b = w * 4 + bb;
      float s = 0.f;
#pragma unroll
      for (int i = 0; i < 16; ++i) s += wr[i] * t[b * 1024 + lane + i * 64];
#pragma unroll
      for (int m = 32; m >= 1; m >>= 1) s += __shfl_xor(s, m, 64);
      if (lane == 0) mod[b * 2048 + j] = s;
    }
  } else if (id < 5120) {
    // split qkv_w row j -> wqk (q,k interleaved per head) or wv
    const int j = id - 2048;
    uint32_t hd = (uint32_t)j / 192u;
    uint32_t rem = (uint32_t)j - hd * 192u;
    ushort* dst = (rem < 128u) ? (wqk + (size_t)(hd * 128u + rem) * 1024)
                               : (wv + (size_t)(hd * 64u + (rem - 128u)) * 1024);
    float4 v = ((const float4*)(qkvw + (size_t)j * 1024))[tid];
    ushort4 o;
    o.x = f2bf(v.x); o.y = f2bf(v.y); o.z = f2bf(v.z); o.w = f2bf(v.w);
    ((ushort4*)dst)[tid] = o;
  } else {
    // wo cast: 1024 blocks x 256 thr x float4
    const int i = (id - 5120) * 256 + tid;   // < 262144
    float4 v = ((const float4*)wow)[i];
    ushort4 o;
    o.x = f2bf(v.x); o.y = f2bf(v.y); o.z = f2bf(v.z); o.w = f2bf(v.w);
    ((ushort4*)wowb)[i] = o;
  }
}

// ---------- RMSNorm + modulate -> bf16 h ----------
__global__ __launch_bounds__(256)
void rms_mod_kernel(const float* __restrict__ x, const float* __restrict__ nw,
                    const float* __restrict__ mod, ushort* __restrict__ h) {
  int row = blockIdx.x;
  int b = row >> 10;
  int tid = threadIdx.x;
  const float4 xv = *(const float4*)(x + (size_t)row * 1024 + tid * 4);
  float ss = xv.x * xv.x + xv.y * xv.y + xv.z * xv.z + xv.w * xv.w;
#pragma unroll
  for (int m = 32; m >= 1; m >>= 1) ss += __shfl_xor(ss, m, 64);
  __shared__ float red[4];
  int w = tid >> 6, lane = tid & 63;
  if (lane == 0) red[w] = ss;
  __syncthreads();
  float tot = red[0] + red[1] + red[2] + red[3];
  float rn = rsqrtf(tot * (1.f / 1024.f) + 1e-6f);
  float4 wv = *(const float4*)(nw + tid * 4);
  float4 sc = *(const float4*)(mod + (size_t)b * 2048 + tid * 4);
  float4 sh = *(const float4*)(mod + (size_t)b * 2048 + 1024 + tid * 4);
  ushort4 o;
  o.x = f2bf(xv.x * rn * wv.x * (1.f + sc.x) + sh.x);
  o.y = f2bf(xv.y * rn * wv.y * (1.f + sc.y) + sh.y);
  o.z = f2bf(xv.z * rn * wv.z * (1.f + sc.z) + sh.z);
  o.w = f2bf(xv.w * rn * wv.w * (1.f + sc.w) + sh.w);
  *(ushort4*)(h + (size_t)row * 1024 + tid * 4) = o;
}

// ---------- QKV GEMM v3: 256x256 tile, BK=64, 8 waves, 2-phase minimal-read ----
// mode1 = q/k proj + fused RoPE, mode2 = V^T.  C[M][N] = A[M][K] * B[N][K]^T.
// Per tile: stage ALL of next tile first (drain lands >=2 phases later),
// B strip persistent in regs (read once), A halves per phase. 24 ds_read_b128,
// 4 barriers, 64 MFMA per tile per wave.
__global__ __launch_bounds__(512, 2)
void gemm_qkv_kernel(const ushort* __restrict__ hbuf, const ushort* __restrict__ wqk,
                     const ushort* __restrict__ wvw,
                     f16* __restrict__ qb, f16* __restrict__ kb,
                     f16* __restrict__ vtb) {
  __shared__ ushort smem[65536];          // 128 KB
  const int id0 = blockIdx.x;
  const int id = (id0 & 7) * 96 + (id0 >> 3);   // XCD swizzle (768 % 8 == 0)
  int mode, m0, n0;
  const ushort *A, *B;
  if (id < 512) {                         // q/k: M=16384 tokens, N=2048 qk-rows
    mode = 1; m0 = (id >> 3) * 256; n0 = (id & 7) * 256; A = hbuf; B = wqk;
  } else {                                // V^T: M=1024 features, N=16384 tokens
    const int i2 = id - 512;
    mode = 2; n0 = (i2 >> 2) * 256; m0 = (i2 & 3) * 256; A = wvw; B = hbuf;
  }
  const int tid = threadIdx.x;
  const int w = tid >> 6, lane = tid & 63, quad = lane >> 4, l15 = lane & 15;
  const int wm = w >> 2, wn = w & 3;      // 2 x 4 wave grid; per-wave C: 128x64

  const int srow = tid >> 3;
  const int sch  = (tid & 7) ^ (srow & 7);
  const int soff = srow * 1024 + sch * 8;           // elems into operand panel
  const ushort* const Abase = A + (size_t)m0 * 1024;
  const ushort* const Bbase = B + (size_t)n0 * 1024;
  ushort* const As0 = smem;                         // 2 x 16384 ushort
  ushort* const Bs0 = smem + 32768;                 // 2 x 16384 ushort
  const int sdst = tid * 8;                         // ushort offset, lane*16B

#define STG_A(d, t, h) do { \
    async16(Abase + (h) * 131072 + soff + (t) * 64,          As0 + (d) * 16384 + (h) * 8192 + sdst); \
    async16(Abase + (h) * 131072 + 65536 + soff + (t) * 64,  As0 + (d) * 16384 + (h) * 8192 + 4096 + sdst); } while (0)
#define STG_B(d, t, h) do { \
    async16(Bbase + (h) * 131072 + soff + (t) * 64,          Bs0 + (d) * 16384 + (h) * 8192 + sdst); \
    async16(Bbase + (h) * 131072 + 65536 + soff + (t) * 64,  Bs0 + (d) * 16384 + (h) * 8192 + 4096 + sdst); } while (0)

  int aoff[2], boff[2];
#pragma unroll
  for (int kk = 0; kk < 2; ++kk) {
    const int swz = (((kk * 4 + quad) ^ (l15 & 7)) * 8);
    aoff[kk] = (wm * 128 + l15) * 64 + swz;
    boff[kk] = (wn * 64 + l15) * 64 + swz;
  }

  const f32x4 fzero = {0.f, 0.f, 0.f, 0.f};
  f32x4 acc[8][4];
#pragma unroll
  for (int a = 0; a < 8; ++a)
#pragma unroll
    for (int b = 0; b < 4; ++b) acc[a][b] = fzero;

  STG_A(0, 0, 0); STG_A(0, 0, 1); STG_B(0, 0, 0); STG_B(0, 0, 1);
  asm volatile("s_waitcnt vmcnt(0)" ::: "memory");
  __builtin_amdgcn_s_barrier();

  bf16x8 af[4][2];   // A half (4 m-frags x 2 k-steps), reused per phase
  bf16x8 bfp[4][2];  // B strip persistent (4 n-frags x 2 k-steps)
#pragma unroll 2
  for (int t = 0; t < 16; ++t) {
    const int cur = t & 1, nxt = cur ^ 1;
    const int tn = (t < 15) ? t + 1 : 15;   // last iter re-stages harmlessly
    const ushort* Asc = As0 + cur * 16384;
    const ushort* Bsc = Bs0 + cur * 16384;

    // ---- phase 0: stage full next tile; read B strip + A rows 0-63 ----
    STG_A(nxt, tn, 0); STG_A(nxt, tn, 1);
    STG_B(nxt, tn, 0); STG_B(nxt, tn, 1);
#pragma unroll
    for (int nf = 0; nf < 4; ++nf)
#pragma unroll
      for (int kk = 0; kk < 2; ++kk)
        bfp[nf][kk] = *(const bf16x8*)(Bsc + nf * 1024 + boff[kk]);
#pragma unroll
    for (int mf = 0; mf < 4; ++mf)
#pragma unroll
      for (int kk = 0; kk < 2; ++kk)
        af[mf][kk] = *(const bf16x8*)(Asc + mf * 1024 + aoff[kk]);
    __builtin_amdgcn_s_barrier();
    __builtin_amdgcn_s_setprio(1);
#pragma unroll
    for (int mf = 0; mf < 4; ++mf)
#pragma unroll
      for (int nf = 0; nf < 4; ++nf)
#pragma unroll
        for (int kk = 0; kk < 2; ++kk)
          acc[mf][nf] = __builtin_amdgcn_mfma_f32_16x16x32_bf16(
              af[mf][kk], bfp[nf][kk], acc[mf][nf], 0, 0, 0);
    __builtin_amdgcn_s_setprio(0);
    __builtin_amdgcn_s_barrier();

    // ---- phase 1: read A rows 64-127; drain next-tile loads at end ----
#pragma unroll
    for (int mf = 0; mf < 4; ++mf)
#pragma unroll
      for (int kk = 0; kk < 2; ++kk)
        af[mf][kk] = *(const bf16x8*)(Asc + (4 + mf) * 1024 + aoff[kk]);
    __builtin_amdgcn_s_barrier();
    __builtin_amdgcn_s_setprio(1);
#pragma unroll
    for (int mf = 0; mf < 4; ++mf)
#pragma unroll
      for (int nf = 0; nf < 4; ++nf)
#pragma unroll
        for (int kk = 0; kk < 2; ++kk)
          acc[4 + mf][nf] = __builtin_amdgcn_mfma_f32_16x16x32_bf16(
              af[mf][kk], bfp[nf][kk], acc[4 + mf][nf], 0, 0, 0);
    __builtin_amdgcn_s_setprio(0);
    asm volatile("s_waitcnt vmcnt(0)" ::: "memory");   // issued ~2 phases ago
    __builtin_amdgcn_s_barrier();
  }
#undef STG_A
#undef STG_B

  // ---- epilogue: wave-private LDS transpose (128x64) -> full-line stores ----
  ushort* eps = smem + w * 8192;          // 16 KB per wave
#pragma unroll
  for (int mf = 0; mf < 8; ++mf)
#pragma unroll
    for (int nf = 0; nf < 4; ++nf)
#pragma unroll
      for (int r = 0; r < 4; ++r) {
        const int row_loc = mf * 16 + quad * 4 + r;
        const int col = nf * 16 + l15;
        const int ch = (col >> 3) ^ (row_loc & 7);
        union { f16 h; ushort u; } cv;
        cv.h = (f16)acc[mf][nf][r];
        eps[row_loc * 64 + ch * 8 + (col & 7)] = cv.u;
      }

  const int ch = lane & 7;
  const int rbase = lane >> 3;
  const int gcol = n0 + wn * 64;
  if (mode == 1) {
    const int hd = gcol >> 7, part = (gcol >> 6) & 1;
    const float QS = part ? 1.f : 0.125f * 1.44269504f;   // q: scale*log2e fold
    f16* const outp = part ? kb : qb;
    float th[4];
#pragma unroll
    for (int t2 = 0; t2 < 4; ++t2)
      th[t2] = __expf(-(float)((ch * 4 + t2) & 15) * 0.5756462732485114f); // ln(1e4)/16
#pragma unroll
    for (int i = 0; i < 16; ++i) {
      const int row_loc = i * 8 + rbase;
      union { uint4 u4; f16 h[8]; } uv;
      uv.u4 = *(const uint4*)(eps + row_loc * 64 + ((ch ^ (row_loc & 7)) * 8));
      const int m = m0 + wm * 128 + row_loc;   // token index
      const int n = m & 1023;
      const float xpos = (float)(n & 31), ypos = (float)(n >> 5);
#pragma unroll
      for (int t2 = 0; t2 < 4; ++t2) {
        const int p = ch * 4 + t2;
        const float pos = (p < 16) ? xpos : ypos;
        float sn, cs;
        __sincosf(pos * th[t2], &sn, &cs);
        const float x0 = (float)uv.h[2 * t2], x1 = (float)uv.h[2 * t2 + 1];
        f16x2 ro = cvt_pkrtz((x0 * cs - x1 * sn) * QS, (x1 * cs + x0 * sn) * QS);
        uv.h[2 * t2] = ro[0];
        uv.h[2 * t2 + 1] = ro[1];
      }
      f16* dst = outp + (((size_t)((m >> 10) * 16 + hd) * 1024 + n) * 64 + ch * 8);
      *(uint4*)dst = uv.u4;
    }
  } else {
    // V^T store with 8B-half swap on rows with bit3 set (attn V bank-conflict
    // fix: LDS read uses half-bit (quad&1)^((row>>3)&1); swap here compensates).
    const int b = gcol >> 10, tb = gcol & 1023;
#pragma unroll
    for (int i = 0; i < 16; ++i) {
      const int row_loc = i * 8 + rbase;
      uint4 v = *(const uint4*)(eps + row_loc * 64 + ((ch ^ (row_loc & 7)) * 8));
      if (i & 1) { unsigned t0 = v.x, t1 = v.y; v.x = v.z; v.y = v.w; v.z = t0; v.w = t1; }
      const int m = m0 + wm * 128 + row_loc;   // feature row
      f16* dst = vtb + ((size_t)(b * 1024 + m) * 1024 + tb + ch * 8);
      *(uint4*)dst = v;
    }
  }
}

// ---------- WO GEMM v2: 256x256 tile, BK=64(=head), 8 waves, 2-phase ----------
// out[16384][1024] fp32 = abuf(head-major) @ wow^T. Grid = 256 blocks = 1/CU.
__global__ __launch_bounds__(512, 2)
void gemm_wo_kernel(const ushort* __restrict__ A, const ushort* __restrict__ B,
                    float* __restrict__ outf) {
  __shared__ ushort smem[65536];          // 128 KB
  const int id0 = blockIdx.x;
  const int id = (id0 & 7) * 32 + (id0 >> 3);   // XCD swizzle (256 % 8 == 0)
  const int m0 = (id >> 2) * 256, n0 = (id & 3) * 256;
  const int tid = threadIdx.x;
  const int w = tid >> 6, lane = tid & 63, quad = lane >> 4, l15 = lane & 15;
  const int wm = w >> 2, wn = w & 3;

  const int srow = tid >> 3;
  const int sch  = (tid & 7) ^ (srow & 7);
  const int soff = srow * 1024 + sch * 8;
  // head-major abuf: elem(token m, k) at ((b*16 + (k>>6))*1024 + (m&1023))*64 + (k&63)
  // K-tile t == head t: A-tile = contiguous 256 rows x 64, row stride 64.
  const int b0 = m0 >> 10, nb = m0 & 1023;
  const ushort* const Abase = A + (size_t)b0 * 16 * 65536 + (size_t)nb * 64;
  const ushort* const Bbase = B + (size_t)n0 * 1024;
  ushort* const As0 = smem;
  ushort* const Bs0 = smem + 32768;
  const int sdst = tid * 8;

#define STG_A(d, t, h) do { \
    async16(Abase + (size_t)(t) * 65536 + ((h) * 128 + srow) * 64 + sch * 8,      As0 + (d) * 16384 + (h) * 8192 + sdst); \
    async16(Abase + (size_t)(t) * 65536 + ((h) * 128 + 64 + srow) * 64 + sch * 8, As0 + (d) * 16384 + (h) * 8192 + 4096 + sdst); } while (0)
#define STG_B(d, t, h) do { \
    async16(Bbase + (h) * 131072 + soff + (t) * 64,          Bs0 + (d) * 16384 + (h) * 8192 + sdst); \
    async16(Bbase + (h) * 131072 + 65536 + soff + (t) * 64,  Bs0 + (d) * 16384 + (h) * 8192 + 4096 + sdst); } while (0)

  int aoff[2], boff[2];
#pragma unroll
  for (int kk = 0; kk < 2; ++kk) {
    const int swz = (((kk * 4 + quad) ^ (l15 & 7)) * 8);
    aoff[kk] = (wm * 128 + l15) * 64 + swz;
    boff[kk] = (wn * 64 + l15) * 64 + swz;
  }

  const f32x4 fzero = {0.f, 0.f, 0.f, 0.f};
  f32x4 acc[8][4];
#pragma unroll
  for (int a = 0; a < 8; ++a)
#pragma unroll
    for (int b = 0; b < 4; ++b) acc[a][b] = fzero;

  STG_A(0, 0, 0); STG_A(0, 0, 1); STG_B(0, 0, 0); STG_B(0, 0, 1);
  asm volatile("s_waitcnt vmcnt(0)" ::: "memory");
  __builtin_amdgcn_s_barrier();

  bf16x8 af[4][2];
  bf16x8 bfp[4][2];
#pragma unroll 2
  for (int t = 0; t < 16; ++t) {
    const int cur = t & 1, nxt = cur ^ 1;
    const int tn = (t < 15) ? t + 1 : 15;
    const ushort* Asc = As0 + cur * 16384;
    const ushort* Bsc = Bs0 + cur * 16384;

    STG_A(nxt, tn, 0); STG_A(nxt, tn, 1);
    STG_B(nxt, tn, 0); STG_B(nxt, tn, 1);
#pragma unroll
    for (int nf = 0; nf < 4; ++nf)
#pragma unroll
      for (int kk = 0; kk < 2; ++kk)
        bfp[nf][kk] = *(const bf16x8*)(Bsc + nf * 1024 + boff[kk]);
#pragma unroll
    for (int mf = 0; mf < 4; ++mf)
#pragma unroll
      for (int kk = 0; kk < 2; ++kk)
        af[mf][kk] = *(const bf16x8*)(Asc + mf * 1024 + aoff[kk]);
    __builtin_amdgcn_s_barrier();
    __builtin_amdgcn_s_setprio(1);
#pragma unroll
    for (int mf = 0; mf < 4; ++mf)
#pragma unroll
      for (int nf = 0; nf < 4; ++nf)
#pragma unroll
        for (int kk = 0; kk < 2; ++kk)
          acc[mf][nf] = __builtin_amdgcn_mfma_f32_16x16x32_bf16(
              af[mf][kk], bfp[nf][kk], acc[mf][nf], 0, 0, 0);
    __builtin_amdgcn_s_setprio(0);
    __builtin_amdgcn_s_barrier();

#pragma unroll
    for (int mf = 0; mf < 4; ++mf)
#pragma unroll
      for (int kk = 0; kk < 2; ++kk)
        af[mf][kk] = *(const bf16x8*)(Asc + (4 + mf) * 1024 + aoff[kk]);
    __builtin_amdgcn_s_barrier();
    __builtin_amdgcn_s_setprio(1);
#pragma unroll
    for (int mf = 0; mf < 4; ++mf)
#pragma unroll
      for (int nf = 0; nf < 4; ++nf)
#pragma unroll
        for (int kk = 0; kk < 2; ++kk)
          acc[4 + mf][nf] = __builtin_amdgcn_mfma_f32_16x16x32_bf16(
              af[mf][kk], bfp[nf][kk], acc[4 + mf][nf], 0, 0, 0);
    __builtin_amdgcn_s_setprio(0);
    asm volatile("s_waitcnt vmcnt(0)" ::: "memory");
    __builtin_amdgcn_s_barrier();
  }
#undef STG_A
#undef STG_B

  // epilogue: direct fp32 stores (final output)
#pragma unroll
  for (int mf = 0; mf < 8; ++mf)
#pragma unroll
    for (int nf = 0; nf < 4; ++nf) {
      const int col = n0 + wn * 64 + nf * 16 + l15;
#pragma unroll
      for (int r = 0; r < 4; ++r) {
        const int row = m0 + wm * 128 + mf * 16 + quad * 4 + r;
        outf[(size_t)row * 1024 + col] = acc[mf][nf][r];
      }
    }
}

// ---------- flash attention v2: dbuf K/V, native exp2, defer-max, V-bank fix ----
__global__ __launch_bounds__(256, 2)
void attn_kernel(const f16* __restrict__ qbuf, const f16* __restrict__ kbuf,
                 const f16* __restrict__ vtbuf, ushort* __restrict__ aout) {
  __shared__ f16 Ks[2][128 * 64];   // [buf][krow][64d], chunk c ^ (row&7)
  __shared__ f16 Vs[2][64 * 128];   // [buf] V^T [d][128k], chunk c ^ (row&15),
                                    //   8B-half pre-swapped in global for row bit3

  const int id = blockIdx.x;
  const int xcd = id & 7, j = id >> 3;
  const int bh = xcd * 32 + (j >> 3);
  const int q0 = (j & 7) * 128;
  const f16* Qg = qbuf + (size_t)bh * 1024 * 64;
  const f16* Kg = kbuf + (size_t)bh * 1024 * 64;
  const f16* Vg = vtbuf + (size_t)bh * 64 * 1024;
  const int tid = threadIdx.x;
  const int w = tid >> 6, lane = tid & 63, quad = lane >> 4, l15 = lane & 15;
  const f32x4 fzero = {0.f, 0.f, 0.f, 0.f};

  // Q B-fragments (x32 layout): B[n=q=l15][k = dc*32 + quad*8 + i]
  f16x8 qf[2][2];
#pragma unroll
  for (int qs = 0; qs < 2; ++qs)
#pragma unroll
    for (int dc = 0; dc < 2; ++dc)
      qf[qs][dc] = *(const f16x8*)(Qg + (size_t)(q0 + w * 32 + qs * 16 + l15) * 64 +
                                   dc * 32 + quad * 8);

  f32x4 oacc[2][4];
#pragma unroll
  for (int qs = 0; qs < 2; ++qs)
#pragma unroll
    for (int ds = 0; ds < 4; ++ds) oacc[qs][ds] = fzero;
  float mrun[2] = {-1e30f, -1e30f}, lrun[2] = {0.f, 0.f};

  // prologue: stage tile 0
#pragma unroll
  for (int i = 0; i < 4; ++i) {
    int u = i * 256 + tid, r = u >> 3, c = u & 7;
    async16(Kg + (size_t)r * 64 + (c ^ (r & 7)) * 8, &Ks[0][u * 8]);
  }
#pragma unroll
  for (int i = 0; i < 4; ++i) {
    int u = i * 256 + tid, r = u >> 4, c = u & 15;
    async16(Vg + (size_t)r * 1024 + (c ^ (r & 15)) * 8, &Vs[0][u * 8]);
  }
  __syncthreads();

#pragma unroll 2
  for (int kt = 0; kt < 1024; kt += 128) {
    const int cur = (kt >> 7) & 1;
    // prefetch next tile into other buffer (issue early, drain at iter end)
    if (kt + 128 < 1024) {
      const int nkt = kt + 128;
#pragma unroll
      for (int i = 0; i < 4; ++i) {
        int u = i * 256 + tid, r = u >> 3, c = u & 7;
        async16(Kg + (size_t)(nkt + r) * 64 + (c ^ (r & 7)) * 8, &Ks[cur ^ 1][u * 8]);
      }
#pragma unroll
      for (int i = 0; i < 4; ++i) {
        int u = i * 256 + tid, r = u >> 4, c = u & 15;
        async16(Vg + (size_t)r * 1024 + nkt + (c ^ (r & 15)) * 8, &Vs[cur ^ 1][u * 8]);
      }
    }
    const f16* Ksc = Ks[cur];
    const f16* Vsc = Vs[cur];

    // S^T = K Q^T via 16x16x32: D[kv=quad*4+r][q=l15]
    f32x4 sacc[2][8];
#pragma unroll
    for (int qs = 0; qs < 2; ++qs)
#pragma unroll
      for (int ks = 0; ks < 8; ++ks) sacc[qs][ks] = fzero;
#pragma unroll
    for (int ks = 0; ks < 8; ++ks) {
#pragma unroll
      for (int dc = 0; dc < 2; ++dc) {
        int row = ks * 16 + l15;
        int ch = (dc * 4 + quad) ^ (row & 7);
        f16x8 kf = *(const f16x8*)(Ksc + row * 64 + ch * 8);
        sacc[0][ks] = __builtin_amdgcn_mfma_f32_16x16x32_f16(kf, qf[0][dc], sacc[0][ks], 0, 0, 0);
        sacc[1][ks] = __builtin_amdgcn_mfma_f32_16x16x32_f16(kf, qf[1][dc], sacc[1][ks], 0, 0, 0);
      }
    }

    // online softmax, defer-max (THR=8 in log2 units), native v_exp_f32
    f16x4 pf[2][8];
#pragma unroll
    for (int qs = 0; qs < 2; ++qs) {
      const float* sv = (const float*)&sacc[qs][0];
      float mx = fmaxf(sv[0], sv[1]);
#pragma unroll
      for (int k = 2; k < 32; k += 2)      // v_max3 pairs
        mx = fmaxf(fmaxf(mx, sv[k]), sv[k + 1]);
      mx = fmaxf(mx, __shfl_xor(mx, 16, 64));
      mx = fmaxf(mx, __shfl_xor(mx, 32, 64));
      if (__any(mx - mrun[qs] > 8.f)) {    // rare: rescale path
        float mnew = fmaxf(mrun[qs], mx);
        float alpha = __builtin_amdgcn_exp2f(mrun[qs] - mnew);
        mrun[qs] = mnew;
        lrun[qs] *= alpha;
        float ar[4];
#pragma unroll
        for (int r = 0; r < 4; ++r) ar[r] = __shfl(alpha, quad * 4 + r, 64);
#pragma unroll
        for (int ds = 0; ds < 4; ++ds)
#pragma unroll
          for (int r = 0; r < 4; ++r) oacc[qs][ds][r] *= ar[r];
      }
      const float mnew = mrun[qs];
      float rs = 0.f;
#pragma unroll
      for (int ks = 0; ks < 8; ++ks) {
        float p0 = __builtin_amdgcn_exp2f(sacc[qs][ks][0] - mnew);
        float p1 = __builtin_amdgcn_exp2f(sacc[qs][ks][1] - mnew);
        float p2 = __builtin_amdgcn_exp2f(sacc[qs][ks][2] - mnew);
        float p3 = __builtin_amdgcn_exp2f(sacc[qs][ks][3] - mnew);
        rs += (p0 + p1) + (p2 + p3);
        union { f16x4 v; f16x2 h[2]; } pu;
        pu.h[0] = cvt_pkrtz(p0, p1);
        pu.h[1] = cvt_pkrtz(p2, p3);
        pf[qs][ks] = pu.v;
      }
      rs += __shfl_xor(rs, 16, 64);
      rs += __shfl_xor(rs, 32, 64);
      lrun[qs] += rs;
    }

    // O += P V : P in x16 A layout; V^T B-frag from LDS (conflict-free banks:
    // half-bit = (quad&1) ^ ((row>>3)&1), matches global pre-swap)
#pragma unroll
    for (int ks = 0; ks < 8; ++ks) {
#pragma unroll
      for (int ds = 0; ds < 4; ++ds) {
        int row = ds * 16 + l15;
        int c16 = ks * 2 + (quad >> 1);
        int half = (quad & 1) ^ ((l15 >> 3) & 1);
        f16x4 vf = *(const f16x4*)(Vsc + row * 128 + ((c16 ^ (row & 15)) * 8) + half * 4);
        oacc[0][ds] = __builtin_amdgcn_mfma_f32_16x16x16f16(pf[0][ks], vf, oacc[0][ds], 0, 0, 0);
        oacc[1][ds] = __builtin_amdgcn_mfma_f32_16x16x16f16(pf[1][ks], vf, oacc[1][ds], 0, 0, 0);
      }
    }
    __syncthreads();   // drains prefetch (vmcnt0) + protects buffer swap
  }

  // epilogue: O /= l -> bf16 via wave-private LDS transpose -> 1KB stores
  // head-major out: aout[(bh*1024 + n)*64 + d]
  ushort* eps = (ushort*)&Ks[0][0] + w * 2048;   // 4KB per wave
#pragma unroll
  for (int qs = 0; qs < 2; ++qs) {
    float linv[4];
#pragma unroll
    for (int r = 0; r < 4; ++r)
      linv[r] = __builtin_amdgcn_rcpf(__shfl(lrun[qs], quad * 4 + r, 64));
#pragma unroll
    for (int ds = 0; ds < 4; ++ds)
#pragma unroll
      for (int r = 0; r < 4; ++r) {
        int row_loc = qs * 16 + quad * 4 + r;
        int col = ds * 16 + l15;
        int ch = (col >> 3) ^ (row_loc & 7);
        eps[row_loc * 64 + ch * 8 + (col & 7)] = f2bf(oacc[qs][ds][r] * linv[r]);
      }
  }
  __syncthreads();
  const size_t obase = ((size_t)bh * 1024 + q0 + w * 32) * 64;
#pragma unroll
  for (int i = 0; i < 4; ++i) {
    int row_loc = i * 8 + (lane >> 3);
    int ch = lane & 7;
    uint4 v = *(const uint4*)(eps + row_loc * 64 + ((ch ^ (row_loc & 7)) * 8));
    *(uint4*)(aout + obase + row_loc * 64 + ch * 8) = v;
  }
}

// ---------- launch ----------
extern "C" void kernel_launch(void* const* d_in, const int* in_sizes, int n_in,
                              void* d_out, int out_size, void* d_ws, size_t ws_size,
                              hipStream_t stream) {
  const float* x    = (const float*)d_in[0];
  const float* t    = (const float*)d_in[1];
  const float* nw   = (const float*)d_in[2];
  const float* mw   = (const float*)d_in[3];
  const float* qkvw = (const float*)d_in[4];
  const float* wow  = (const float*)d_in[5];
  float* out = (float*)d_out;
  char* ws = (char*)d_ws;

  float*  modbuf  = (float*)(ws);                    // 131072 B
  ushort* hbuf    = (ushort*)(ws + 131072);          // 32 MB (bf16)
  ushort* wqk_b   = (ushort*)(ws + 33685504);        // 4 MB
  ushort* wv_b    = (ushort*)(ws + 37879808);        // 2 MB
  ushort* wow_b   = (ushort*)(ws + 39976960);        // 2 MB
  f16*    qbuf    = (f16*)(ws + 42074112);           // 32 MB (rope+scale applied)
  f16*    kbuf    = (f16*)(ws + 75628544);           // 32 MB (rope applied)
  f16*    vtbuf   = (f16*)(ws + 109182976);          // 32 MB (V^T, half-swapped rows)
  ushort* abuf    = (ushort*)(ws + 142737408);       // 32 MB (bf16, head-major)

  prep_kernel<<<dim3(6144), dim3(256), 0, stream>>>(
      t, mw, modbuf, qkvw, wqk_b, wv_b, wow, wow_b);
  rms_mod_kernel<<<dim3(16384), dim3(256), 0, stream>>>(x, nw, modbuf, hbuf);
  gemm_qkv_kernel<<<dim3(768), dim3(512), 0, stream>>>(
      hbuf, wqk_b, wv_b, qbuf, kbuf, vtbuf);
  attn_kernel<<<dim3(2048), dim3(256), 0, stream>>>(qbuf, kbuf, vtbuf, abuf);
  gemm_wo_kernel<<<dim3(256), dim3(512), 0, stream>>>(abuf, wow_b, out);
}

// Round 5
// 384.746 us; speedup vs baseline: 1.1823x; 1.0172x over previous
//
#include <hip/hip_runtime.h>
#include <stdint.h>

// ---------- types ----------
typedef __bf16    bf16x8 __attribute__((ext_vector_type(8)));
typedef float     f32x4  __attribute__((ext_vector_type(4)));
typedef _Float16  f16;
typedef _Float16  f16x2  __attribute__((ext_vector_type(2)));
typedef _Float16  f16x4  __attribute__((ext_vector_type(4)));
typedef _Float16  f16x8  __attribute__((ext_vector_type(8)));

#define DEV __device__ __forceinline__

DEV ushort f2bf(float f) {               // RTNE float -> bf16 bits
  union { float f; uint32_t u; } v; v.f = f;
  uint32_t u = v.u;
  return (ushort)((u + 0x7fffu + ((u >> 16) & 1u)) >> 16);
}

DEV f16x2 cvt_pkrtz(float a, float b) {  // v_cvt_pkrtz_f16_f32, bit-cast to f16x2
  return __builtin_bit_cast(f16x2, __builtin_amdgcn_cvt_pkrtz(a, b));
}

// async global->LDS, 16B per lane. LDS dest must be wave-uniform base + lane*16.
DEV void async16(const void* g, void* l) {
  __builtin_amdgcn_global_load_lds(
      (__attribute__((address_space(1))) void*)(uintptr_t)g,
      (__attribute__((address_space(3))) void*)(uint32_t)(uintptr_t)l,
      16, 0, 0);
}

// ---------- prep kernel: mod-gemm + weight split/cast + wo cast (one launch) ----
__global__ __launch_bounds__(256)
void prep_kernel(const float* __restrict__ t, const float* __restrict__ mw,
                 float* __restrict__ mod,
                 const float* __restrict__ qkvw, ushort* __restrict__ wqk,
                 ushort* __restrict__ wv,
                 const float* __restrict__ wow, ushort* __restrict__ wowb) {
  const int id = blockIdx.x;
  const int tid = threadIdx.x;
  if (id < 2048) {
    // mod = t @ mod_w.T : column j, wave w handles batches w*4..w*4+3
    const int j = id;
    const int w = tid >> 6, lane = tid & 63;
    float wr[16];
#pragma unroll
    for (int i = 0; i < 16; ++i) wr[i] = mw[(size_t)j * 1024 + lane + i * 64];
#pragma unroll
    for (int bb = 0; bb < 4; ++bb) {
      int b = w * 4 + bb;
      float s = 0.f;
#pragma unroll
      for (int i = 0; i < 16; ++i) s += wr[i] * t[b * 1024 + lane + i * 64];
#pragma unroll
      for (int m = 32; m >= 1; m >>= 1) s += __shfl_xor(s, m, 64);
      if (lane == 0) mod[b * 2048 + j] = s;
    }
  } else if (id < 5120) {
    // split qkv_w row j -> wqk (q,k interleaved per head) or wv
    const int j = id - 2048;
    uint32_t hd = (uint32_t)j / 192u;
    uint32_t rem = (uint32_t)j - hd * 192u;
    ushort* dst = (rem < 128u) ? (wqk + (size_t)(hd * 128u + rem) * 1024)
                               : (wv + (size_t)(hd * 64u + (rem - 128u)) * 1024);
    float4 v = ((const float4*)(qkvw + (size_t)j * 1024))[tid];
    ushort4 o;
    o.x = f2bf(v.x); o.y = f2bf(v.y); o.z = f2bf(v.z); o.w = f2bf(v.w);
    ((ushort4*)dst)[tid] = o;
  } else {
    // wo cast: 1024 blocks x 256 thr x float4
    const int i = (id - 5120) * 256 + tid;   // < 262144
    float4 v = ((const float4*)wow)[i];
    ushort4 o;
    o.x = f2bf(v.x); o.y = f2bf(v.y); o.z = f2bf(v.z); o.w = f2bf(v.w);
    ((ushort4*)wowb)[i] = o;
  }
}

// ---------- RMSNorm + modulate -> bf16 h ----------
__global__ __launch_bounds__(256)
void rms_mod_kernel(const float* __restrict__ x, const float* __restrict__ nw,
                    const float* __restrict__ mod, ushort* __restrict__ h) {
  int row = blockIdx.x;
  int b = row >> 10;
  int tid = threadIdx.x;
  const float4 xv = *(const float4*)(x + (size_t)row * 1024 + tid * 4);
  float ss = xv.x * xv.x + xv.y * xv.y + xv.z * xv.z + xv.w * xv.w;
#pragma unroll
  for (int m = 32; m >= 1; m >>= 1) ss += __shfl_xor(ss, m, 64);
  __shared__ float red[4];
  int w = tid >> 6, lane = tid & 63;
  if (lane == 0) red[w] = ss;
  __syncthreads();
  float tot = red[0] + red[1] + red[2] + red[3];
  float rn = rsqrtf(tot * (1.f / 1024.f) + 1e-6f);
  float4 wv = *(const float4*)(nw + tid * 4);
  float4 sc = *(const float4*)(mod + (size_t)b * 2048 + tid * 4);
  float4 sh = *(const float4*)(mod + (size_t)b * 2048 + 1024 + tid * 4);
  ushort4 o;
  o.x = f2bf(xv.x * rn * wv.x * (1.f + sc.x) + sh.x);
  o.y = f2bf(xv.y * rn * wv.y * (1.f + sc.y) + sh.y);
  o.z = f2bf(xv.z * rn * wv.z * (1.f + sc.z) + sh.z);
  o.w = f2bf(xv.w * rn * wv.w * (1.f + sc.w) + sh.w);
  *(ushort4*)(h + (size_t)row * 1024 + tid * 4) = o;
}

// ---------- shared GEMM helpers (8-phase schedule) ----------
DEV void lda2(bf16x8 (&af)[4][2], const ushort* base, const int (&aoff)[2]) {
#pragma unroll
  for (int mf = 0; mf < 4; ++mf)
#pragma unroll
    for (int kk = 0; kk < 2; ++kk)
      af[mf][kk] = *(const bf16x8*)(base + mf * 1024 + aoff[kk]);
}
DEV void ldb2(bf16x8 (&bf)[2][2], const ushort* base, const int (&boff)[2]) {
#pragma unroll
  for (int nf = 0; nf < 2; ++nf)
#pragma unroll
    for (int kk = 0; kk < 2; ++kk)
      bf[nf][kk] = *(const bf16x8*)(base + nf * 1024 + boff[kk]);
}
template <int MH, int NH>
DEV void mm16(f32x4 (&acc)[8][4], const bf16x8 (&af)[4][2], const bf16x8 (&bf)[2][2]) {
#pragma unroll
  for (int mf = 0; mf < 4; ++mf)
#pragma unroll
    for (int nf = 0; nf < 2; ++nf)
#pragma unroll
      for (int kk = 0; kk < 2; ++kk)
        acc[MH * 4 + mf][NH * 2 + nf] = __builtin_amdgcn_mfma_f32_16x16x32_bf16(
            af[mf][kk], bf[nf][kk], acc[MH * 4 + mf][NH * 2 + nf], 0, 0, 0);
}
#define BARR __builtin_amdgcn_s_barrier()
#define PRIO1 __builtin_amdgcn_s_setprio(1)
#define PRIO0 __builtin_amdgcn_s_setprio(0)
#define VMC4 asm volatile("s_waitcnt vmcnt(4)" ::: "memory")
#define VMC0 asm volatile("s_waitcnt vmcnt(0)" ::: "memory")

// ---------- QKV GEMM v4b: 256x256, BK=64, 8 waves, 8-phase counted-vmcnt -----
// Hazard rule: a stage into region R issues only after the barrier following
// R's last read.  Buf A last read @ph2/ph6 -> A stages at ph3/ph7 (both halves).
// Buf B last read @ph3/ph7 -> B stages at ph4/ph0 (next tile's B). vmcnt(4)
// at ph3/ph7 only; never 0 in main loop.
__global__ __launch_bounds__(512, 2)
void gemm_qkv_kernel(const ushort* __restrict__ hbuf, const ushort* __restrict__ wqk,
                     const ushort* __restrict__ wvw,
                     f16* __restrict__ qb, f16* __restrict__ kb,
                     f16* __restrict__ vtb) {
  __shared__ ushort smem[65536];          // 128 KB
  const int id0 = blockIdx.x;
  const int id = (id0 & 7) * 96 + (id0 >> 3);   // XCD swizzle (768 % 8 == 0)
  int mode, m0, n0;
  const ushort *A, *B;
  if (id < 512) {                         // q/k: M=16384 tokens, N=2048 qk-rows
    mode = 1; m0 = (id >> 3) * 256; n0 = (id & 7) * 256; A = hbuf; B = wqk;
  } else {                                // V^T: M=1024 features, N=16384 tokens
    const int i2 = id - 512;
    mode = 2; n0 = (i2 >> 2) * 256; m0 = (i2 & 3) * 256; A = wvw; B = hbuf;
  }
  const int tid = threadIdx.x;
  const int w = tid >> 6, lane = tid & 63, quad = lane >> 4, l15 = lane & 15;
  const int wm = w >> 2, wn = w & 3;      // 2 x 4 wave grid; per-wave C: 128x64

  const int srow = tid >> 3;
  const int sch  = (tid & 7) ^ (srow & 7);
  const int soff = srow * 1024 + sch * 8;           // elems into operand panel
  const ushort* const Abase = A + (size_t)m0 * 1024;
  const ushort* const Bbase = B + (size_t)n0 * 1024;
  ushort* const As0 = smem;                         // 2 bufs x 16384 ushort
  ushort* const Bs0 = smem + 32768;
  const int sdst = tid * 8;                         // ushort offset, lane*16B

#define STG_A(d, t, h) do { \
    async16(Abase + (h) * 131072 + soff + (t) * 64,          As0 + (d) * 16384 + (h) * 8192 + sdst); \
    async16(Abase + (h) * 131072 + 65536 + soff + (t) * 64,  As0 + (d) * 16384 + (h) * 8192 + 4096 + sdst); } while (0)
#define STG_B(d, t, h) do { \
    async16(Bbase + (h) * 131072 + soff + (t) * 64,          Bs0 + (d) * 16384 + (h) * 8192 + sdst); \
    async16(Bbase + (h) * 131072 + 65536 + soff + (t) * 64,  Bs0 + (d) * 16384 + (h) * 8192 + 4096 + sdst); } while (0)

  int aoff[2], boff[2];
#pragma unroll
  for (int kk = 0; kk < 2; ++kk) {
    const int swz = (((kk * 4 + quad) ^ (l15 & 7)) * 8);
    aoff[kk] = (wm * 128 + l15) * 64 + swz;
    boff[kk] = (wn * 64 + l15) * 64 + swz;
  }

  const f32x4 fzero = {0.f, 0.f, 0.f, 0.f};
  f32x4 acc[8][4];
#pragma unroll
  for (int a = 0; a < 8; ++a)
#pragma unroll
    for (int b = 0; b < 4; ++b) acc[a][b] = fzero;

  bf16x8 af[4][2];    // current A half (32 VGPR)
  bf16x8 bfA[2][2];   // wave-local B col-half 0 (16 VGPR)
  bf16x8 bfB[2][2];   // wave-local B col-half 1 (16 VGPR)

  // prologue: t0 fully {A0,A1,B0,B1}; t1's A halves. (issue order = retire order)
  STG_A(0, 0, 0); STG_A(0, 0, 1); STG_B(0, 0, 0); STG_B(0, 0, 1);
  STG_A(1, 1, 0); STG_A(1, 1, 1);
  VMC4;                                   // t0's 8 loads retired; t1's A in flight
  BARR;

#pragma unroll 1
  for (int i = 0; i < 7; ++i) {           // tiles 0..13 (tail handles 14,15)
    const int t1 = 2 * i + 1, u0 = 2 * i + 2, u1 = 2 * i + 3;
    // ph0: buf0 A0 + Bh0; stage t1's B halves (buf1 B: last read ph7-prev)
    lda2(af, As0, aoff);
    ldb2(bfA, Bs0, boff);
    STG_B(1, t1, 0); STG_B(1, t1, 1);
    BARR; PRIO1; mm16<0, 0>(acc, af, bfA); PRIO0; BARR;
    // ph1: Bh1 (no stage)
    ldb2(bfB, Bs0 + 2048, boff);
    BARR; PRIO1; mm16<0, 1>(acc, af, bfB); PRIO0; BARR;
    // ph2: A1 (no stage; buf0 A still being read)
    lda2(af, As0 + 4096, aoff);
    BARR; PRIO1; mm16<1, 1>(acc, af, bfB); PRIO0; BARR;
    // ph3: Bh0 re-read; stage BOTH A halves of u0 (buf0 A last read ph2);
    //      counted wait -> buf1 tile t1 ready
    ldb2(bfA, Bs0, boff);
    STG_A(0, u0, 0); STG_A(0, u0, 1);
    BARR; PRIO1; mm16<1, 0>(acc, af, bfA); PRIO0;
    VMC4; BARR;
    // ph4: buf1 A0 + Bh0; stage B halves of u0 (buf0 B last read ph3)
    lda2(af, As0 + 16384, aoff);
    ldb2(bfA, Bs0 + 16384, boff);
    STG_B(0, u0, 0); STG_B(0, u0, 1);
    BARR; PRIO1; mm16<0, 0>(acc, af, bfA); PRIO0; BARR;
    // ph5: Bh1 (no stage)
    ldb2(bfB, Bs0 + 16384 + 2048, boff);
    BARR; PRIO1; mm16<0, 1>(acc, af, bfB); PRIO0; BARR;
    // ph6: A1 (no stage)
    lda2(af, As0 + 16384 + 4096, aoff);
    BARR; PRIO1; mm16<1, 1>(acc, af, bfB); PRIO0; BARR;
    // ph7: Bh0 re-read; stage BOTH A halves of u1 (buf1 A last read ph6);
    //      counted wait -> buf0 tile u0 ready
    ldb2(bfA, Bs0 + 16384, boff);
    STG_A(1, u1, 0); STG_A(1, u1, 1);
    BARR; PRIO1; mm16<1, 0>(acc, af, bfA); PRIO0;
    VMC4; BARR;
  }
  // tail: tiles 14 (buf0), 15 (buf1); only ph0 stages (B halves of 15)
  lda2(af, As0, aoff); ldb2(bfA, Bs0, boff);
  STG_B(1, 15, 0); STG_B(1, 15, 1);
  BARR; PRIO1; mm16<0, 0>(acc, af, bfA); PRIO0; BARR;
  ldb2(bfB, Bs0 + 2048, boff);
  BARR; PRIO1; mm16<0, 1>(acc, af, bfB); PRIO0; BARR;
  lda2(af, As0 + 4096, aoff);
  BARR; PRIO1; mm16<1, 1>(acc, af, bfB); PRIO0; BARR;
  ldb2(bfA, Bs0, boff);
  BARR; PRIO1; mm16<1, 0>(acc, af, bfA); PRIO0;
  VMC0; BARR;                             // tile 15 fully landed
  lda2(af, As0 + 16384, aoff); ldb2(bfA, Bs0 + 16384, boff);
  BARR; PRIO1; mm16<0, 0>(acc, af, bfA); PRIO0; BARR;
  ldb2(bfB, Bs0 + 16384 + 2048, boff);
  BARR; PRIO1; mm16<0, 1>(acc, af, bfB); PRIO0; BARR;
  lda2(af, As0 + 16384 + 4096, aoff);
  BARR; PRIO1; mm16<1, 1>(acc, af, bfB); PRIO0; BARR;
  ldb2(bfA, Bs0 + 16384, boff);
  BARR; PRIO1; mm16<1, 0>(acc, af, bfA); PRIO0; BARR;
#undef STG_A
#undef STG_B

  // ---- epilogue: wave-private LDS transpose (128x64) -> full-line stores ----
  ushort* eps = smem + w * 8192;          // 16 KB per wave
#pragma unroll
  for (int mf = 0; mf < 8; ++mf)
#pragma unroll
    for (int nf = 0; nf < 4; ++nf)
#pragma unroll
      for (int r = 0; r < 4; ++r) {
        const int row_loc = mf * 16 + quad * 4 + r;
        const int col = nf * 16 + l15;
        const int ch = (col >> 3) ^ (row_loc & 7);
        union { f16 h; ushort u; } cv;
        cv.h = (f16)acc[mf][nf][r];
        eps[row_loc * 64 + ch * 8 + (col & 7)] = cv.u;
      }

  const int ch = lane & 7;
  const int rbase = lane >> 3;
  const int gcol = n0 + wn * 64;
  if (mode == 1) {
    const int hd = gcol >> 7, part = (gcol >> 6) & 1;
    const float QS = part ? 1.f : 0.125f * 1.44269504f;   // q: scale*log2e fold
    f16* const outp = part ? kb : qb;
    float th[4];
#pragma unroll
    for (int t2 = 0; t2 < 4; ++t2)
      th[t2] = __expf(-(float)((ch * 4 + t2) & 15) * 0.5756462732485114f); // ln(1e4)/16
#pragma unroll
    for (int i = 0; i < 16; ++i) {
      const int row_loc = i * 8 + rbase;
      union { uint4 u4; f16 h[8]; } uv;
      uv.u4 = *(const uint4*)(eps + row_loc * 64 + ((ch ^ (row_loc & 7)) * 8));
      const int m = m0 + wm * 128 + row_loc;   // token index
      const int n = m & 1023;
      const float xpos = (float)(n & 31), ypos = (float)(n >> 5);
#pragma unroll
      for (int t2 = 0; t2 < 4; ++t2) {
        const int p = ch * 4 + t2;
        const float pos = (p < 16) ? xpos : ypos;
        float sn, cs;
        __sincosf(pos * th[t2], &sn, &cs);
        const float x0 = (float)uv.h[2 * t2], x1 = (float)uv.h[2 * t2 + 1];
        f16x2 ro = cvt_pkrtz((x0 * cs - x1 * sn) * QS, (x1 * cs + x0 * sn) * QS);
        uv.h[2 * t2] = ro[0];
        uv.h[2 * t2 + 1] = ro[1];
      }
      f16* dst = outp + (((size_t)((m >> 10) * 16 + hd) * 1024 + n) * 64 + ch * 8);
      *(uint4*)dst = uv.u4;
    }
  } else {
    // V^T store with 8B-half swap on rows with bit3 set (attn V bank-conflict
    // fix: LDS read uses half-bit (quad&1)^((row>>3)&1); swap here compensates).
    const int b = gcol >> 10, tb = gcol & 1023;
#pragma unroll
    for (int i = 0; i < 16; ++i) {
      const int row_loc = i * 8 + rbase;
      uint4 v = *(const uint4*)(eps + row_loc * 64 + ((ch ^ (row_loc & 7)) * 8));
      if (i & 1) { unsigned t0 = v.x, t1 = v.y; v.x = v.z; v.y = v.w; v.z = t0; v.w = t1; }
      const int m = m0 + wm * 128 + row_loc;   // feature row
      f16* dst = vtb + ((size_t)(b * 1024 + m) * 1024 + tb + ch * 8);
      *(uint4*)dst = v;
    }
  }
}

// ---------- WO GEMM v2: 256x256 tile, BK=64(=head), 8 waves, 2-phase ----------
// out[16384][1024] fp32 = abuf(head-major) @ wow^T. Grid = 256 blocks = 1/CU.
__global__ __launch_bounds__(512, 2)
void gemm_wo_kernel(const ushort* __restrict__ A, const ushort* __restrict__ B,
                    float* __restrict__ outf) {
  __shared__ ushort smem[65536];          // 128 KB
  const int id0 = blockIdx.x;
  const int id = (id0 & 7) * 32 + (id0 >> 3);   // XCD swizzle (256 % 8 == 0)
  const int m0 = (id >> 2) * 256, n0 = (id & 3) * 256;
  const int tid = threadIdx.x;
  const int w = tid >> 6, lane = tid & 63, quad = lane >> 4, l15 = lane & 15;
  const int wm = w >> 2, wn = w & 3;

  const int srow = tid >> 3;
  const int sch  = (tid & 7) ^ (srow & 7);
  const int soff = srow * 1024 + sch * 8;
  const int b0 = m0 >> 10, nb = m0 & 1023;
  const ushort* const Abase = A + (size_t)b0 * 16 * 65536 + (size_t)nb * 64;
  const ushort* const Bbase = B + (size_t)n0 * 1024;
  ushort* const As0 = smem;
  ushort* const Bs0 = smem + 32768;
  const int sdst = tid * 8;

#define STG_A(d, t, h) do { \
    async16(Abase + (size_t)(t) * 65536 + ((h) * 128 + srow) * 64 + sch * 8,      As0 + (d) * 16384 + (h) * 8192 + sdst); \
    async16(Abase + (size_t)(t) * 65536 + ((h) * 128 + 64 + srow) * 64 + sch * 8, As0 + (d) * 16384 + (h) * 8192 + 4096 + sdst); } while (0)
#define STG_B(d, t, h) do { \
    async16(Bbase + (h) * 131072 + soff + (t) * 64,          Bs0 + (d) * 16384 + (h) * 8192 + sdst); \
    async16(Bbase + (h) * 131072 + 65536 + soff + (t) * 64,  Bs0 + (d) * 16384 + (h) * 8192 + 4096 + sdst); } while (0)

  int aoff[2], boff[2];
#pragma unroll
  for (int kk = 0; kk < 2; ++kk) {
    const int swz = (((kk * 4 + quad) ^ (l15 & 7)) * 8);
    aoff[kk] = (wm * 128 + l15) * 64 + swz;
    boff[kk] = (wn * 64 + l15) * 64 + swz;
  }

  const f32x4 fzero = {0.f, 0.f, 0.f, 0.f};
  f32x4 acc[8][4];
#pragma unroll
  for (int a = 0; a < 8; ++a)
#pragma unroll
    for (int b = 0; b < 4; ++b) acc[a][b] = fzero;

  bf16x8 af[4][2];
  bf16x8 bfp[4][2];
  STG_A(0, 0, 0); STG_A(0, 0, 1); STG_B(0, 0, 0); STG_B(0, 0, 1);
  VMC0;
  BARR;

#pragma unroll 2
  for (int t = 0; t < 16; ++t) {
    const int cur = t & 1, nxt = cur ^ 1;
    const int tn = (t < 15) ? t + 1 : 15;
    const ushort* Asc = As0 + cur * 16384;
    const ushort* Bsc = Bs0 + cur * 16384;

    STG_A(nxt, tn, 0); STG_A(nxt, tn, 1);
    STG_B(nxt, tn, 0); STG_B(nxt, tn, 1);
#pragma unroll
    for (int nf = 0; nf < 4; ++nf)
#pragma unroll
      for (int kk = 0; kk < 2; ++kk)
        bfp[nf][kk] = *(const bf16x8*)(Bsc + nf * 1024 + boff[kk]);
#pragma unroll
    for (int mf = 0; mf < 4; ++mf)
#pragma unroll
      for (int kk = 0; kk < 2; ++kk)
        af[mf][kk] = *(const bf16x8*)(Asc + mf * 1024 + aoff[kk]);
    BARR; PRIO1;
#pragma unroll
    for (int mf = 0; mf < 4; ++mf)
#pragma unroll
      for (int nf = 0; nf < 4; ++nf)
#pragma unroll
        for (int kk = 0; kk < 2; ++kk)
          acc[mf][nf] = __builtin_amdgcn_mfma_f32_16x16x32_bf16(
              af[mf][kk], bfp[nf][kk], acc[mf][nf], 0, 0, 0);
    PRIO0; BARR;

#pragma unroll
    for (int mf = 0; mf < 4; ++mf)
#pragma unroll
      for (int kk = 0; kk < 2; ++kk)
        af[mf][kk] = *(const bf16x8*)(Asc + (4 + mf) * 1024 + aoff[kk]);
    BARR; PRIO1;
#pragma unroll
    for (int mf = 0; mf < 4; ++mf)
#pragma unroll
      for (int nf = 0; nf < 4; ++nf)
#pragma unroll
        for (int kk = 0; kk < 2; ++kk)
          acc[4 + mf][nf] = __builtin_amdgcn_mfma_f32_16x16x32_bf16(
              af[mf][kk], bfp[nf][kk], acc[4 + mf][nf], 0, 0, 0);
    PRIO0;
    VMC0;
    BARR;
  }
#undef STG_A
#undef STG_B

  // epilogue: direct fp32 stores (final output)
#pragma unroll
  for (int mf = 0; mf < 8; ++mf)
#pragma unroll
    for (int nf = 0; nf < 4; ++nf) {
      const int col = n0 + wn * 64 + nf * 16 + l15;
#pragma unroll
      for (int r = 0; r < 4; ++r) {
        const int row = m0 + wm * 128 + mf * 16 + quad * 4 + r;
        outf[(size_t)row * 1024 + col] = acc[mf][nf][r];
      }
    }
}

// ---------- flash attention v3: KVBLK=64, 32KB LDS, 4+ blocks/CU ----------
__global__ __launch_bounds__(256, 4)
void attn_kernel(const f16* __restrict__ qbuf, const f16* __restrict__ kbuf,
                 const f16* __restrict__ vtbuf, ushort* __restrict__ aout) {
  __shared__ f16 Ks[2][64 * 64];   // [buf][krow][64d], chunk c ^ (row&7)
  __shared__ f16 Vs[2][64 * 64];   // [buf] V^T [d][64k], chunk c ^ (row&7),
                                   //   8B-half pre-swapped in global for d bit3

  const int id = blockIdx.x;
  const int xcd = id & 7, j = id >> 3;
  const int bh = xcd * 32 + (j >> 3);
  const int q0 = (j & 7) * 128;
  const f16* Qg = qbuf + (size_t)bh * 1024 * 64;
  const f16* Kg = kbuf + (size_t)bh * 1024 * 64;
  const f16* Vg = vtbuf + (size_t)bh * 64 * 1024;
  const int tid = threadIdx.x;
  const int w = tid >> 6, lane = tid & 63, quad = lane >> 4, l15 = lane & 15;
  const f32x4 fzero = {0.f, 0.f, 0.f, 0.f};

  // Q B-fragments (x32 layout): B[n=q=l15][k = dc*32 + quad*8 + i]
  f16x8 qf[2][2];
#pragma unroll
  for (int qs = 0; qs < 2; ++qs)
#pragma unroll
    for (int dc = 0; dc < 2; ++dc)
      qf[qs][dc] = *(const f16x8*)(Qg + (size_t)(q0 + w * 32 + qs * 16 + l15) * 64 +
                                   dc * 32 + quad * 8);

  f32x4 oacc[2][4];
#pragma unroll
  for (int qs = 0; qs < 2; ++qs)
#pragma unroll
    for (int ds = 0; ds < 4; ++ds) oacc[qs][ds] = fzero;
  float mrun[2] = {-1e30f, -1e30f}, lrun[2] = {0.f, 0.f};

  // prologue: stage tile 0 (K 8KB + V 8KB, 2+2 async16/lane)
#pragma unroll
  for (int i = 0; i < 2; ++i) {
    int u = i * 256 + tid, r = u >> 3, c = u & 7;
    async16(Kg + (size_t)r * 64 + (c ^ (r & 7)) * 8, &Ks[0][u * 8]);
  }
#pragma unroll
  for (int i = 0; i < 2; ++i) {
    int u = i * 256 + tid, r = u >> 3, c = u & 7;
    async16(Vg + (size_t)r * 1024 + (c ^ (r & 7)) * 8, &Vs[0][u * 8]);
  }
  __syncthreads();

#pragma unroll 2
  for (int kt = 0; kt < 1024; kt += 64) {
    const int cur = (kt >> 6) & 1;
    // prefetch next tile into other buffer
    if (kt + 64 < 1024) {
      const int nkt = kt + 64;
#pragma unroll
      for (int i = 0; i < 2; ++i) {
        int u = i * 256 + tid, r = u >> 3, c = u & 7;
        async16(Kg + (size_t)(nkt + r) * 64 + (c ^ (r & 7)) * 8, &Ks[cur ^ 1][u * 8]);
      }
#pragma unroll
      for (int i = 0; i < 2; ++i) {
        int u = i * 256 + tid, r = u >> 3, c = u & 7;
        async16(Vg + (size_t)r * 1024 + nkt + (c ^ (r & 7)) * 8, &Vs[cur ^ 1][u * 8]);
      }
    }
    const f16* Ksc = Ks[cur];
    const f16* Vsc = Vs[cur];

    // S^T = K Q^T via 16x16x32: D[kv=quad*4+r][q=l15]
    f32x4 sacc[2][4];
#pragma unroll
    for (int qs = 0; qs < 2; ++qs)
#pragma unroll
      for (int ks = 0; ks < 4; ++ks) sacc[qs][ks] = fzero;
#pragma unroll
    for (int ks = 0; ks < 4; ++ks) {
#pragma unroll
      for (int dc = 0; dc < 2; ++dc) {
        int row = ks * 16 + l15;
        int ch = (dc * 4 + quad) ^ (row & 7);
        f16x8 kf = *(const f16x8*)(Ksc + row * 64 + ch * 8);
        sacc[0][ks] = __builtin_amdgcn_mfma_f32_16x16x32_f16(kf, qf[0][dc], sacc[0][ks], 0, 0, 0);
        sacc[1][ks] = __builtin_amdgcn_mfma_f32_16x16x32_f16(kf, qf[1][dc], sacc[1][ks], 0, 0, 0);
      }
    }

    // online softmax, defer-max (THR=8 in log2 units), native v_exp_f32
    f16x4 pf[2][4];
#pragma unroll
    for (int qs = 0; qs < 2; ++qs) {
      const float* sv = (const float*)&sacc[qs][0];
      float mx = fmaxf(sv[0], sv[1]);
#pragma unroll
      for (int k = 2; k < 16; k += 2)      // v_max3 pairs
        mx = fmaxf(fmaxf(mx, sv[k]), sv[k + 1]);
      mx = fmaxf(mx, __shfl_xor(mx, 16, 64));
      mx = fmaxf(mx, __shfl_xor(mx, 32, 64));
      if (__any(mx - mrun[qs] > 8.f)) {    // rare: rescale path
        float mnew = fmaxf(mrun[qs], mx);
        float alpha = __builtin_amdgcn_exp2f(mrun[qs] - mnew);
        mrun[qs] = mnew;
        lrun[qs] *= alpha;
        float ar[4];
#pragma unroll
        for (int r = 0; r < 4; ++r) ar[r] = __shfl(alpha, quad * 4 + r, 64);
#pragma unroll
        for (int ds = 0; ds < 4; ++ds)
#pragma unroll
          for (int r = 0; r < 4; ++r) oacc[qs][ds][r] *= ar[r];
      }
      const float mnew = mrun[qs];
      float rs = 0.f;
#pragma unroll
      for (int ks = 0; ks < 4; ++ks) {
        float p0 = __builtin_amdgcn_exp2f(sacc[qs][ks][0] - mnew);
        float p1 = __builtin_amdgcn_exp2f(sacc[qs][ks][1] - mnew);
        float p2 = __builtin_amdgcn_exp2f(sacc[qs][ks][2] - mnew);
        float p3 = __builtin_amdgcn_exp2f(sacc[qs][ks][3] - mnew);
        rs += (p0 + p1) + (p2 + p3);
        union { f16x4 v; f16x2 h[2]; } pu;
        pu.h[0] = cvt_pkrtz(p0, p1);
        pu.h[1] = cvt_pkrtz(p2, p3);
        pf[qs][ks] = pu.v;
      }
      rs += __shfl_xor(rs, 16, 64);
      rs += __shfl_xor(rs, 32, 64);
      lrun[qs] += rs;
    }

    // O += P V : P in x16 A layout; V^T B-frag from LDS (conflict-free banks:
    // half-bit = (quad&1) ^ ((d>>3)&1), matches global pre-swap)
#pragma unroll
    for (int ks = 0; ks < 4; ++ks) {
#pragma unroll
      for (int ds = 0; ds < 4; ++ds) {
        int row = ds * 16 + l15;
        int c16 = ks * 2 + (quad >> 1);
        int half = (quad & 1) ^ ((l15 >> 3) & 1);
        f16x4 vf = *(const f16x4*)(Vsc + row * 64 + ((c16 ^ (row & 7)) * 8) + half * 4);
        oacc[0][ds] = __builtin_amdgcn_mfma_f32_16x16x16f16(pf[0][ks], vf, oacc[0][ds], 0, 0, 0);
        oacc[1][ds] = __builtin_amdgcn_mfma_f32_16x16x16f16(pf[1][ks], vf, oacc[1][ds], 0, 0, 0);
      }
    }
    __syncthreads();   // drains prefetch (vmcnt0) + protects buffer swap
  }

  // epilogue: O /= l -> bf16 via wave-private LDS transpose -> 1KB stores
  // head-major out: aout[(bh*1024 + n)*64 + d]
  ushort* eps = (ushort*)&Ks[0][0] + w * 2048;   // 4KB per wave = 16KB = Ks
#pragma unroll
  for (int qs = 0; qs < 2; ++qs) {
    float linv[4];
#pragma unroll
    for (int r = 0; r < 4; ++r)
      linv[r] = __builtin_amdgcn_rcpf(__shfl(lrun[qs], quad * 4 + r, 64));
#pragma unroll
    for (int ds = 0; ds < 4; ++ds)
#pragma unroll
      for (int r = 0; r < 4; ++r) {
        int row_loc = qs * 16 + quad * 4 + r;
        int col = ds * 16 + l15;
        int ch = (col >> 3) ^ (row_loc & 7);
        eps[row_loc * 64 + ch * 8 + (col & 7)] = f2bf(oacc[qs][ds][r] * linv[r]);
      }
  }
  __syncthreads();
  const size_t obase = ((size_t)bh * 1024 + q0 + w * 32) * 64;
#pragma unroll
  for (int i = 0; i < 4; ++i) {
    int row_loc = i * 8 + (lane >> 3);
    int ch = lane & 7;
    uint4 v = *(const uint4*)(eps + row_loc * 64 + ((ch ^ (row_loc & 7)) * 8));
    *(uint4*)(aout + obase + row_loc * 64 + ch * 8) = v;
  }
}

// ---------- launch ----------
extern "C" void kernel_launch(void* const* d_in, const int* in_sizes, int n_in,
                              void* d_out, int out_size, void* d_ws, size_t ws_size,
                              hipStream_t stream) {
  const float* x    = (const float*)d_in[0];
  const float* t    = (const float*)d_in[1];
  const float* nw   = (const float*)d_in[2];
  const float* mw   = (const float*)d_in[3];
  const float* qkvw = (const float*)d_in[4];
  const float* wow  = (const float*)d_in[5];
  float* out = (float*)d_out;
  char* ws = (char*)d_ws;

  float*  modbuf  = (float*)(ws);                    // 131072 B
  ushort* hbuf    = (ushort*)(ws + 131072);          // 32 MB (bf16)
  ushort* wqk_b   = (ushort*)(ws + 33685504);        // 4 MB
  ushort* wv_b    = (ushort*)(ws + 37879808);        // 2 MB
  ushort* wow_b   = (ushort*)(ws + 39976960);        // 2 MB
  f16*    qbuf    = (f16*)(ws + 42074112);           // 32 MB (rope+scale applied)
  f16*    kbuf    = (f16*)(ws + 75628544);           // 32 MB (rope applied)
  f16*    vtbuf   = (f16*)(ws + 109182976);          // 32 MB (V^T, half-swapped rows)
  ushort* abuf    = (ushort*)(ws + 142737408);       // 32 MB (bf16, head-major)

  prep_kernel<<<dim3(6144), dim3(256), 0, stream>>>(
      t, mw, modbuf, qkvw, wqk_b, wv_b, wow, wow_b);
  rms_mod_kernel<<<dim3(16384), dim3(256), 0, stream>>>(x, nw, modbuf, hbuf);
  gemm_qkv_kernel<<<dim3(768), dim3(512), 0, stream>>>(
      hbuf, wqk_b, wv_b, qbuf, kbuf, vtbuf);
  attn_kernel<<<dim3(2048), dim3(256), 0, stream>>>(qbuf, kbuf, vtbuf, abuf);
  gemm_wo_kernel<<<dim3(256), dim3(512), 0, stream>>>(abuf, wow_b, out);
}

// Round 6
// 384.252 us; speedup vs baseline: 1.1838x; 1.0013x over previous
//
#include <hip/hip_runtime.h>
#include <stdint.h>

// ---------- types ----------
typedef __bf16    bf16x8 __attribute__((ext_vector_type(8)));
typedef float     f32x4  __attribute__((ext_vector_type(4)));
typedef _Float16  f16;
typedef _Float16  f16x2  __attribute__((ext_vector_type(2)));
typedef _Float16  f16x4  __attribute__((ext_vector_type(4)));
typedef _Float16  f16x8  __attribute__((ext_vector_type(8)));

#define DEV __device__ __forceinline__

DEV ushort f2bf(float f) {               // RTNE float -> bf16 bits
  union { float f; uint32_t u; } v; v.f = f;
  uint32_t u = v.u;
  return (ushort)((u + 0x7fffu + ((u >> 16) & 1u)) >> 16);
}

DEV f16x2 cvt_pkrtz(float a, float b) {  // v_cvt_pkrtz_f16_f32, bit-cast to f16x2
  return __builtin_bit_cast(f16x2, __builtin_amdgcn_cvt_pkrtz(a, b));
}

// async global->LDS, 16B per lane. LDS dest must be wave-uniform base + lane*16.
DEV void async16(const void* g, void* l) {
  __builtin_amdgcn_global_load_lds(
      (__attribute__((address_space(1))) void*)(uintptr_t)g,
      (__attribute__((address_space(3))) void*)(uint32_t)(uintptr_t)l,
      16, 0, 0);
}

// ---------- prep kernel: mod-gemm + weight split/cast + wo cast (one launch) ----
__global__ __launch_bounds__(256)
void prep_kernel(const float* __restrict__ t, const float* __restrict__ mw,
                 float* __restrict__ mod,
                 const float* __restrict__ qkvw, ushort* __restrict__ wqk,
                 ushort* __restrict__ wv,
                 const float* __restrict__ wow, ushort* __restrict__ wowb) {
  const int id = blockIdx.x;
  const int tid = threadIdx.x;
  if (id < 2048) {
    // mod = t @ mod_w.T : column j, wave w handles batches w*4..w*4+3
    const int j = id;
    const int w = tid >> 6, lane = tid & 63;
    float wr[16];
#pragma unroll
    for (int i = 0; i < 16; ++i) wr[i] = mw[(size_t)j * 1024 + lane + i * 64];
#pragma unroll
    for (int bb = 0; bb < 4; ++bb) {
      int b = w * 4 + bb;
      float s = 0.f;
#pragma unroll
      for (int i = 0; i < 16; ++i) s += wr[i] * t[b * 1024 + lane + i * 64];
#pragma unroll
      for (int m = 32; m >= 1; m >>= 1) s += __shfl_xor(s, m, 64);
      if (lane == 0) mod[b * 2048 + j] = s;
    }
  } else if (id < 5120) {
    // split qkv_w row j -> wqk (q,k interleaved per head) or wv
    const int j = id - 2048;
    uint32_t hd = (uint32_t)j / 192u;
    uint32_t rem = (uint32_t)j - hd * 192u;
    ushort* dst = (rem < 128u) ? (wqk + (size_t)(hd * 128u + rem) * 1024)
                               : (wv + (size_t)(hd * 64u + (rem - 128u)) * 1024);
    float4 v = ((const float4*)(qkvw + (size_t)j * 1024))[tid];
    ushort4 o;
    o.x = f2bf(v.x); o.y = f2bf(v.y); o.z = f2bf(v.z); o.w = f2bf(v.w);
    ((ushort4*)dst)[tid] = o;
  } else {
    // wo cast: 1024 blocks x 256 thr x float4
    const int i = (id - 5120) * 256 + tid;   // < 262144
    float4 v = ((const float4*)wow)[i];
    ushort4 o;
    o.x = f2bf(v.x); o.y = f2bf(v.y); o.z = f2bf(v.z); o.w = f2bf(v.w);
    ((ushort4*)wowb)[i] = o;
  }
}

// ---------- RMSNorm + modulate -> bf16 h ----------
__global__ __launch_bounds__(256)
void rms_mod_kernel(const float* __restrict__ x, const float* __restrict__ nw,
                    const float* __restrict__ mod, ushort* __restrict__ h) {
  int row = blockIdx.x;
  int b = row >> 10;
  int tid = threadIdx.x;
  const float4 xv = *(const float4*)(x + (size_t)row * 1024 + tid * 4);
  float ss = xv.x * xv.x + xv.y * xv.y + xv.z * xv.z + xv.w * xv.w;
#pragma unroll
  for (int m = 32; m >= 1; m >>= 1) ss += __shfl_xor(ss, m, 64);
  __shared__ float red[4];
  int w = tid >> 6, lane = tid & 63;
  if (lane == 0) red[w] = ss;
  __syncthreads();
  float tot = red[0] + red[1] + red[2] + red[3];
  float rn = rsqrtf(tot * (1.f / 1024.f) + 1e-6f);
  float4 wv = *(const float4*)(nw + tid * 4);
  float4 sc = *(const float4*)(mod + (size_t)b * 2048 + tid * 4);
  float4 sh = *(const float4*)(mod + (size_t)b * 2048 + 1024 + tid * 4);
  ushort4 o;
  o.x = f2bf(xv.x * rn * wv.x * (1.f + sc.x) + sh.x);
  o.y = f2bf(xv.y * rn * wv.y * (1.f + sc.y) + sh.y);
  o.z = f2bf(xv.z * rn * wv.z * (1.f + sc.z) + sh.z);
  o.w = f2bf(xv.w * rn * wv.w * (1.f + sc.w) + sh.w);
  *(ushort4*)(h + (size_t)row * 1024 + tid * 4) = o;
}

// ---------- shared GEMM helpers ----------
DEV void lda2(bf16x8 (&af)[4][2], const ushort* base, const int (&aoff)[2]) {
#pragma unroll
  for (int mf = 0; mf < 4; ++mf)
#pragma unroll
    for (int kk = 0; kk < 2; ++kk)
      af[mf][kk] = *(const bf16x8*)(base + mf * 1024 + aoff[kk]);
}
#define PRIO1 __builtin_amdgcn_s_setprio(1)
#define PRIO0 __builtin_amdgcn_s_setprio(0)

// ---------- QKV GEMM v5: 256x256, BK=64, 8 waves, 1 barrier per K-tile -------
// mode1 = q/k proj + fused RoPE, mode2 = V^T.  C[M][N] = A[M][K] * B[N][K]^T.
// Per tile: stage next tile (other buffer) at top, B strip persistent in regs
// (8 reads), A halves 8+8, two 32-MFMA clusters, ONE __syncthreads (its
// vmcnt(0) drains stages issued a full tile earlier). No intra-tile barriers:
// waves desync so one wave's ds_reads overlap another's MFMAs.
__global__ __launch_bounds__(512, 2)
void gemm_qkv_kernel(const ushort* __restrict__ hbuf, const ushort* __restrict__ wqk,
                     const ushort* __restrict__ wvw,
                     f16* __restrict__ qb, f16* __restrict__ kb,
                     f16* __restrict__ vtb) {
  __shared__ ushort smem[65536];          // 128 KB
  const int id0 = blockIdx.x;
  const int id = (id0 & 7) * 96 + (id0 >> 3);   // XCD swizzle (768 % 8 == 0)
  int mode, m0, n0;
  const ushort *A, *B;
  if (id < 512) {                         // q/k: M=16384 tokens, N=2048 qk-rows
    mode = 1; m0 = (id >> 3) * 256; n0 = (id & 7) * 256; A = hbuf; B = wqk;
  } else {                                // V^T: M=1024 features, N=16384 tokens
    const int i2 = id - 512;
    mode = 2; n0 = (i2 >> 2) * 256; m0 = (i2 & 3) * 256; A = wvw; B = hbuf;
  }
  const int tid = threadIdx.x;
  const int w = tid >> 6, lane = tid & 63, quad = lane >> 4, l15 = lane & 15;
  const int wm = w >> 2, wn = w & 3;      // 2 x 4 wave grid; per-wave C: 128x64

  const int srow = tid >> 3;
  const int sch  = (tid & 7) ^ (srow & 7);
  const int soff = srow * 1024 + sch * 8;           // elems into operand panel
  const ushort* const Abase = A + (size_t)m0 * 1024;
  const ushort* const Bbase = B + (size_t)n0 * 1024;
  ushort* const As0 = smem;                         // 2 bufs x 16384 ushort
  ushort* const Bs0 = smem + 32768;
  const int sdst = tid * 8;                         // ushort offset, lane*16B

#define STG_A(d, t, h) do { \
    async16(Abase + (h) * 131072 + soff + (t) * 64,          As0 + (d) * 16384 + (h) * 8192 + sdst); \
    async16(Abase + (h) * 131072 + 65536 + soff + (t) * 64,  As0 + (d) * 16384 + (h) * 8192 + 4096 + sdst); } while (0)
#define STG_B(d, t, h) do { \
    async16(Bbase + (h) * 131072 + soff + (t) * 64,          Bs0 + (d) * 16384 + (h) * 8192 + sdst); \
    async16(Bbase + (h) * 131072 + 65536 + soff + (t) * 64,  Bs0 + (d) * 16384 + (h) * 8192 + 4096 + sdst); } while (0)

  int aoff[2], boff[2];
#pragma unroll
  for (int kk = 0; kk < 2; ++kk) {
    const int swz = (((kk * 4 + quad) ^ (l15 & 7)) * 8);
    aoff[kk] = (wm * 128 + l15) * 64 + swz;
    boff[kk] = (wn * 64 + l15) * 64 + swz;
  }

  const f32x4 fzero = {0.f, 0.f, 0.f, 0.f};
  f32x4 acc[8][4];
#pragma unroll
  for (int a = 0; a < 8; ++a)
#pragma unroll
    for (int b = 0; b < 4; ++b) acc[a][b] = fzero;

  bf16x8 af[4][2];    // current A half (32 VGPR)
  bf16x8 bfp[4][2];   // B strip persistent (32 VGPR)

  // prologue: stage tile 0 into buf0; syncthreads drains (vmcnt0) + barrier
  STG_A(0, 0, 0); STG_A(0, 0, 1); STG_B(0, 0, 0); STG_B(0, 0, 1);
  __syncthreads();

#pragma unroll 2
  for (int t = 0; t < 16; ++t) {
    const int cur = t & 1, nxt = cur ^ 1;
    const int tn = (t < 15) ? t + 1 : 15;   // last iter re-stages harmlessly
    const ushort* Asc = As0 + cur * 16384;
    const ushort* Bsc = Bs0 + cur * 16384;

    // stage next tile into other buffer: legal (all waves' reads of buf[nxt]
    // preceded the previous __syncthreads)
    STG_A(nxt, tn, 0); STG_A(nxt, tn, 1);
    STG_B(nxt, tn, 0); STG_B(nxt, tn, 1);

    // B strip (8 reads) + A half 0 (8 reads) -> 32 MFMA
#pragma unroll
    for (int nf = 0; nf < 4; ++nf)
#pragma unroll
      for (int kk = 0; kk < 2; ++kk)
        bfp[nf][kk] = *(const bf16x8*)(Bsc + nf * 1024 + boff[kk]);
    lda2(af, Asc, aoff);
    PRIO1;
#pragma unroll
    for (int mf = 0; mf < 4; ++mf)
#pragma unroll
      for (int nf = 0; nf < 4; ++nf)
#pragma unroll
        for (int kk = 0; kk < 2; ++kk)
          acc[mf][nf] = __builtin_amdgcn_mfma_f32_16x16x32_bf16(
              af[mf][kk], bfp[nf][kk], acc[mf][nf], 0, 0, 0);
    PRIO0;
    // A half 1 (8 reads) -> 32 MFMA
    lda2(af, Asc + 4096, aoff);
    PRIO1;
#pragma unroll
    for (int mf = 0; mf < 4; ++mf)
#pragma unroll
      for (int nf = 0; nf < 4; ++nf)
#pragma unroll
        for (int kk = 0; kk < 2; ++kk)
          acc[4 + mf][nf] = __builtin_amdgcn_mfma_f32_16x16x32_bf16(
              af[mf][kk], bfp[nf][kk], acc[4 + mf][nf], 0, 0, 0);
    PRIO0;
    __syncthreads();   // vmcnt(0): next tile landed (issued a full tile ago)
  }
#undef STG_A
#undef STG_B

  // ---- epilogue: wave-private LDS transpose (128x64) -> full-line stores ----
  ushort* eps = smem + w * 8192;          // 16 KB per wave
#pragma unroll
  for (int mf = 0; mf < 8; ++mf)
#pragma unroll
    for (int nf = 0; nf < 4; ++nf)
#pragma unroll
      for (int r = 0; r < 4; ++r) {
        const int row_loc = mf * 16 + quad * 4 + r;
        const int col = nf * 16 + l15;
        const int ch = (col >> 3) ^ (row_loc & 7);
        union { f16 h; ushort u; } cv;
        cv.h = (f16)acc[mf][nf][r];
        eps[row_loc * 64 + ch * 8 + (col & 7)] = cv.u;
      }

  const int ch = lane & 7;
  const int rbase = lane >> 3;
  const int gcol = n0 + wn * 64;
  if (mode == 1) {
    const int hd = gcol >> 7, part = (gcol >> 6) & 1;
    const float QS = part ? 1.f : 0.125f * 1.44269504f;   // q: scale*log2e fold
    f16* const outp = part ? kb : qb;
    float th[4];
#pragma unroll
    for (int t2 = 0; t2 < 4; ++t2)
      th[t2] = __expf(-(float)((ch * 4 + t2) & 15) * 0.5756462732485114f); // ln(1e4)/16
#pragma unroll
    for (int i = 0; i < 16; ++i) {
      const int row_loc = i * 8 + rbase;
      union { uint4 u4; f16 h[8]; } uv;
      uv.u4 = *(const uint4*)(eps + row_loc * 64 + ((ch ^ (row_loc & 7)) * 8));
      const int m = m0 + wm * 128 + row_loc;   // token index
      const int n = m & 1023;
      const float xpos = (float)(n & 31), ypos = (float)(n >> 5);
#pragma unroll
      for (int t2 = 0; t2 < 4; ++t2) {
        const int p = ch * 4 + t2;
        const float pos = (p < 16) ? xpos : ypos;
        float sn, cs;
        __sincosf(pos * th[t2], &sn, &cs);
        const float x0 = (float)uv.h[2 * t2], x1 = (float)uv.h[2 * t2 + 1];
        f16x2 ro = cvt_pkrtz((x0 * cs - x1 * sn) * QS, (x1 * cs + x0 * sn) * QS);
        uv.h[2 * t2] = ro[0];
        uv.h[2 * t2 + 1] = ro[1];
      }
      f16* dst = outp + (((size_t)((m >> 10) * 16 + hd) * 1024 + n) * 64 + ch * 8);
      *(uint4*)dst = uv.u4;
    }
  } else {
    // V^T store with 8B-half swap on rows with bit3 set (attn V bank-conflict
    // fix: LDS read uses half-bit (quad&1)^((d>>3)&1); swap here compensates).
    const int b = gcol >> 10, tb = gcol & 1023;
#pragma unroll
    for (int i = 0; i < 16; ++i) {
      const int row_loc = i * 8 + rbase;
      uint4 v = *(const uint4*)(eps + row_loc * 64 + ((ch ^ (row_loc & 7)) * 8));
      if (i & 1) { unsigned t0 = v.x, t1 = v.y; v.x = v.z; v.y = v.w; v.z = t0; v.w = t1; }
      const int m = m0 + wm * 128 + row_loc;   // feature row
      f16* dst = vtb + ((size_t)(b * 1024 + m) * 1024 + tb + ch * 8);
      *(uint4*)dst = v;
    }
  }
}

// ---------- WO GEMM v3: 256x256, BK=64(=head), 8 waves, 1 barrier per tile ----
// out[16384][1024] fp32 = abuf(head-major) @ wow^T. Grid = 256 blocks = 1/CU.
__global__ __launch_bounds__(512, 2)
void gemm_wo_kernel(const ushort* __restrict__ A, const ushort* __restrict__ B,
                    float* __restrict__ outf) {
  __shared__ ushort smem[65536];          // 128 KB
  const int id0 = blockIdx.x;
  const int id = (id0 & 7) * 32 + (id0 >> 3);   // XCD swizzle (256 % 8 == 0)
  const int m0 = (id >> 2) * 256, n0 = (id & 3) * 256;
  const int tid = threadIdx.x;
  const int w = tid >> 6, lane = tid & 63, quad = lane >> 4, l15 = lane & 15;
  const int wm = w >> 2, wn = w & 3;

  const int srow = tid >> 3;
  const int sch  = (tid & 7) ^ (srow & 7);
  const int soff = srow * 1024 + sch * 8;
  const int b0 = m0 >> 10, nb = m0 & 1023;
  const ushort* const Abase = A + (size_t)b0 * 16 * 65536 + (size_t)nb * 64;
  const ushort* const Bbase = B + (size_t)n0 * 1024;
  ushort* const As0 = smem;
  ushort* const Bs0 = smem + 32768;
  const int sdst = tid * 8;

#define STG_A(d, t, h) do { \
    async16(Abase + (size_t)(t) * 65536 + ((h) * 128 + srow) * 64 + sch * 8,      As0 + (d) * 16384 + (h) * 8192 + sdst); \
    async16(Abase + (size_t)(t) * 65536 + ((h) * 128 + 64 + srow) * 64 + sch * 8, As0 + (d) * 16384 + (h) * 8192 + 4096 + sdst); } while (0)
#define STG_B(d, t, h) do { \
    async16(Bbase + (h) * 131072 + soff + (t) * 64,          Bs0 + (d) * 16384 + (h) * 8192 + sdst); \
    async16(Bbase + (h) * 131072 + 65536 + soff + (t) * 64,  Bs0 + (d) * 16384 + (h) * 8192 + 4096 + sdst); } while (0)

  int aoff[2], boff[2];
#pragma unroll
  for (int kk = 0; kk < 2; ++kk) {
    const int swz = (((kk * 4 + quad) ^ (l15 & 7)) * 8);
    aoff[kk] = (wm * 128 + l15) * 64 + swz;
    boff[kk] = (wn * 64 + l15) * 64 + swz;
  }

  const f32x4 fzero = {0.f, 0.f, 0.f, 0.f};
  f32x4 acc[8][4];
#pragma unroll
  for (int a = 0; a < 8; ++a)
#pragma unroll
    for (int b = 0; b < 4; ++b) acc[a][b] = fzero;

  bf16x8 af[4][2];
  bf16x8 bfp[4][2];
  STG_A(0, 0, 0); STG_A(0, 0, 1); STG_B(0, 0, 0); STG_B(0, 0, 1);
  __syncthreads();

#pragma unroll 2
  for (int t = 0; t < 16; ++t) {
    const int cur = t & 1, nxt = cur ^ 1;
    const int tn = (t < 15) ? t + 1 : 15;
    const ushort* Asc = As0 + cur * 16384;
    const ushort* Bsc = Bs0 + cur * 16384;

    STG_A(nxt, tn, 0); STG_A(nxt, tn, 1);
    STG_B(nxt, tn, 0); STG_B(nxt, tn, 1);
#pragma unroll
    for (int nf = 0; nf < 4; ++nf)
#pragma unroll
      for (int kk = 0; kk < 2; ++kk)
        bfp[nf][kk] = *(const bf16x8*)(Bsc + nf * 1024 + boff[kk]);
    lda2(af, Asc, aoff);
    PRIO1;
#pragma unroll
    for (int mf = 0; mf < 4; ++mf)
#pragma unroll
      for (int nf = 0; nf < 4; ++nf)
#pragma unroll
        for (int kk = 0; kk < 2; ++kk)
          acc[mf][nf] = __builtin_amdgcn_mfma_f32_16x16x32_bf16(
              af[mf][kk], bfp[nf][kk], acc[mf][nf], 0, 0, 0);
    PRIO0;
    lda2(af, Asc + 4096, aoff);
    PRIO1;
#pragma unroll
    for (int mf = 0; mf < 4; ++mf)
#pragma unroll
      for (int nf = 0; nf < 4; ++nf)
#pragma unroll
        for (int kk = 0; kk < 2; ++kk)
          acc[4 + mf][nf] = __builtin_amdgcn_mfma_f32_16x16x32_bf16(
              af[mf][kk], bfp[nf][kk], acc[4 + mf][nf], 0, 0, 0);
    PRIO0;
    __syncthreads();
  }
#undef STG_A
#undef STG_B

  // epilogue: direct fp32 stores (final output)
#pragma unroll
  for (int mf = 0; mf < 8; ++mf)
#pragma unroll
    for (int nf = 0; nf < 4; ++nf) {
      const int col = n0 + wn * 64 + nf * 16 + l15;
#pragma unroll
      for (int r = 0; r < 4; ++r) {
        const int row = m0 + wm * 128 + mf * 16 + quad * 4 + r;
        outf[(size_t)row * 1024 + col] = acc[mf][nf][r];
      }
    }
}

// ---------- flash attention v3: KVBLK=64, 32KB LDS, 4+ blocks/CU ----------
__global__ __launch_bounds__(256, 4)
void attn_kernel(const f16* __restrict__ qbuf, const f16* __restrict__ kbuf,
                 const f16* __restrict__ vtbuf, ushort* __restrict__ aout) {
  __shared__ f16 Ks[2][64 * 64];   // [buf][krow][64d], chunk c ^ (row&7)
  __shared__ f16 Vs[2][64 * 64];   // [buf] V^T [d][64k], chunk c ^ (row&7),
                                   //   8B-half pre-swapped in global for d bit3

  const int id = blockIdx.x;
  const int xcd = id & 7, j = id >> 3;
  const int bh = xcd * 32 + (j >> 3);
  const int q0 = (j & 7) * 128;
  const f16* Qg = qbuf + (size_t)bh * 1024 * 64;
  const f16* Kg = kbuf + (size_t)bh * 1024 * 64;
  const f16* Vg = vtbuf + (size_t)bh * 64 * 1024;
  const int tid = threadIdx.x;
  const int w = tid >> 6, lane = tid & 63, quad = lane >> 4, l15 = lane & 15;
  const f32x4 fzero = {0.f, 0.f, 0.f, 0.f};

  // Q B-fragments (x32 layout): B[n=q=l15][k = dc*32 + quad*8 + i]
  f16x8 qf[2][2];
#pragma unroll
  for (int qs = 0; qs < 2; ++qs)
#pragma unroll
    for (int dc = 0; dc < 2; ++dc)
      qf[qs][dc] = *(const f16x8*)(Qg + (size_t)(q0 + w * 32 + qs * 16 + l15) * 64 +
                                   dc * 32 + quad * 8);

  f32x4 oacc[2][4];
#pragma unroll
  for (int qs = 0; qs < 2; ++qs)
#pragma unroll
    for (int ds = 0; ds < 4; ++ds) oacc[qs][ds] = fzero;
  float mrun[2] = {-1e30f, -1e30f}, lrun[2] = {0.f, 0.f};

  // prologue: stage tile 0 (K 8KB + V 8KB, 2+2 async16/lane)
#pragma unroll
  for (int i = 0; i < 2; ++i) {
    int u = i * 256 + tid, r = u >> 3, c = u & 7;
    async16(Kg + (size_t)r * 64 + (c ^ (r & 7)) * 8, &Ks[0][u * 8]);
  }
#pragma unroll
  for (int i = 0; i < 2; ++i) {
    int u = i * 256 + tid, r = u >> 3, c = u & 7;
    async16(Vg + (size_t)r * 1024 + (c ^ (r & 7)) * 8, &Vs[0][u * 8]);
  }
  __syncthreads();

#pragma unroll 2
  for (int kt = 0; kt < 1024; kt += 64) {
    const int cur = (kt >> 6) & 1;
    // prefetch next tile into other buffer
    if (kt + 64 < 1024) {
      const int nkt = kt + 64;
#pragma unroll
      for (int i = 0; i < 2; ++i) {
        int u = i * 256 + tid, r = u >> 3, c = u & 7;
        async16(Kg + (size_t)(nkt + r) * 64 + (c ^ (r & 7)) * 8, &Ks[cur ^ 1][u * 8]);
      }
#pragma unroll
      for (int i = 0; i < 2; ++i) {
        int u = i * 256 + tid, r = u >> 3, c = u & 7;
        async16(Vg + (size_t)r * 1024 + nkt + (c ^ (r & 7)) * 8, &Vs[cur ^ 1][u * 8]);
      }
    }
    const f16* Ksc = Ks[cur];
    const f16* Vsc = Vs[cur];

    // S^T = K Q^T via 16x16x32: D[kv=quad*4+r][q=l15]
    f32x4 sacc[2][4];
#pragma unroll
    for (int qs = 0; qs < 2; ++qs)
#pragma unroll
      for (int ks = 0; ks < 4; ++ks) sacc[qs][ks] = fzero;
#pragma unroll
    for (int ks = 0; ks < 4; ++ks) {
#pragma unroll
      for (int dc = 0; dc < 2; ++dc) {
        int row = ks * 16 + l15;
        int ch = (dc * 4 + quad) ^ (row & 7);
        f16x8 kf = *(const f16x8*)(Ksc + row * 64 + ch * 8);
        sacc[0][ks] = __builtin_amdgcn_mfma_f32_16x16x32_f16(kf, qf[0][dc], sacc[0][ks], 0, 0, 0);
        sacc[1][ks] = __builtin_amdgcn_mfma_f32_16x16x32_f16(kf, qf[1][dc], sacc[1][ks], 0, 0, 0);
      }
    }

    // online softmax, defer-max (THR=8 in log2 units), native v_exp_f32
    f16x4 pf[2][4];
#pragma unroll
    for (int qs = 0; qs < 2; ++qs) {
      const float* sv = (const float*)&sacc[qs][0];
      float mx = fmaxf(sv[0], sv[1]);
#pragma unroll
      for (int k = 2; k < 16; k += 2)      // v_max3 pairs
        mx = fmaxf(fmaxf(mx, sv[k]), sv[k + 1]);
      mx = fmaxf(mx, __shfl_xor(mx, 16, 64));
      mx = fmaxf(mx, __shfl_xor(mx, 32, 64));
      if (__any(mx - mrun[qs] > 8.f)) {    // rare: rescale path
        float mnew = fmaxf(mrun[qs], mx);
        float alpha = __builtin_amdgcn_exp2f(mrun[qs] - mnew);
        mrun[qs] = mnew;
        lrun[qs] *= alpha;
        float ar[4];
#pragma unroll
        for (int r = 0; r < 4; ++r) ar[r] = __shfl(alpha, quad * 4 + r, 64);
#pragma unroll
        for (int ds = 0; ds < 4; ++ds)
#pragma unroll
          for (int r = 0; r < 4; ++r) oacc[qs][ds][r] *= ar[r];
      }
      const float mnew = mrun[qs];
      float rs = 0.f;
#pragma unroll
      for (int ks = 0; ks < 4; ++ks) {
        float p0 = __builtin_amdgcn_exp2f(sacc[qs][ks][0] - mnew);
        float p1 = __builtin_amdgcn_exp2f(sacc[qs][ks][1] - mnew);
        float p2 = __builtin_amdgcn_exp2f(sacc[qs][ks][2] - mnew);
        float p3 = __builtin_amdgcn_exp2f(sacc[qs][ks][3] - mnew);
        rs += (p0 + p1) + (p2 + p3);
        union { f16x4 v; f16x2 h[2]; } pu;
        pu.h[0] = cvt_pkrtz(p0, p1);
        pu.h[1] = cvt_pkrtz(p2, p3);
        pf[qs][ks] = pu.v;
      }
      rs += __shfl_xor(rs, 16, 64);
      rs += __shfl_xor(rs, 32, 64);
      lrun[qs] += rs;
    }

    // O += P V : P in x16 A layout; V^T B-frag from LDS (conflict-free banks:
    // half-bit = (quad&1) ^ ((d>>3)&1), matches global pre-swap)
#pragma unroll
    for (int ks = 0; ks < 4; ++ks) {
#pragma unroll
      for (int ds = 0; ds < 4; ++ds) {
        int row = ds * 16 + l15;
        int c16 = ks * 2 + (quad >> 1);
        int half = (quad & 1) ^ ((l15 >> 3) & 1);
        f16x4 vf = *(const f16x4*)(Vsc + row * 64 + ((c16 ^ (row & 7)) * 8) + half * 4);
        oacc[0][ds] = __builtin_amdgcn_mfma_f32_16x16x16f16(pf[0][ks], vf, oacc[0][ds], 0, 0, 0);
        oacc[1][ds] = __builtin_amdgcn_mfma_f32_16x16x16f16(pf[1][ks], vf, oacc[1][ds], 0, 0, 0);
      }
    }
    __syncthreads();   // drains prefetch (vmcnt0) + protects buffer swap
  }

  // epilogue: O /= l -> bf16 via wave-private LDS transpose -> 1KB stores
  // head-major out: aout[(bh*1024 + n)*64 + d]
  ushort* eps = (ushort*)&Ks[0][0] + w * 2048;   // 4KB per wave = 16KB = Ks
#pragma unroll
  for (int qs = 0; qs < 2; ++qs) {
    float linv[4];
#pragma unroll
    for (int r = 0; r < 4; ++r)
      linv[r] = __builtin_amdgcn_rcpf(__shfl(lrun[qs], quad * 4 + r, 64));
#pragma unroll
    for (int ds = 0; ds < 4; ++ds)
#pragma unroll
      for (int r = 0; r < 4; ++r) {
        int row_loc = qs * 16 + quad * 4 + r;
        int col = ds * 16 + l15;
        int ch = (col >> 3) ^ (row_loc & 7);
        eps[row_loc * 64 + ch * 8 + (col & 7)] = f2bf(oacc[qs][ds][r] * linv[r]);
      }
  }
  __syncthreads();
  const size_t obase = ((size_t)bh * 1024 + q0 + w * 32) * 64;
#pragma unroll
  for (int i = 0; i < 4; ++i) {
    int row_loc = i * 8 + (lane >> 3);
    int ch = lane & 7;
    uint4 v = *(const uint4*)(eps + row_loc * 64 + ((ch ^ (row_loc & 7)) * 8));
    *(uint4*)(aout + obase + row_loc * 64 + ch * 8) = v;
  }
}

// ---------- launch ----------
extern "C" void kernel_launch(void* const* d_in, const int* in_sizes, int n_in,
                              void* d_out, int out_size, void* d_ws, size_t ws_size,
                              hipStream_t stream) {
  const float* x    = (const float*)d_in[0];
  const float* t    = (const float*)d_in[1];
  const float* nw   = (const float*)d_in[2];
  const float* mw   = (const float*)d_in[3];
  const float* qkvw = (const float*)d_in[4];
  const float* wow  = (const float*)d_in[5];
  float* out = (float*)d_out;
  char* ws = (char*)d_ws;

  float*  modbuf  = (float*)(ws);                    // 131072 B
  ushort* hbuf    = (ushort*)(ws + 131072);          // 32 MB (bf16)
  ushort* wqk_b   = (ushort*)(ws + 33685504);        // 4 MB
  ushort* wv_b    = (ushort*)(ws + 37879808);        // 2 MB
  ushort* wow_b   = (ushort*)(ws + 39976960);        // 2 MB
  f16*    qbuf    = (f16*)(ws + 42074112);           // 32 MB (rope+scale applied)
  f16*    kbuf    = (f16*)(ws + 75628544);           // 32 MB (rope applied)
  f16*    vtbuf   = (f16*)(ws + 109182976);          // 32 MB (V^T, half-swapped rows)
  ushort* abuf    = (ushort*)(ws + 142737408);       // 32 MB (bf16, head-major)

  prep_kernel<<<dim3(6144), dim3(256), 0, stream>>>(
      t, mw, modbuf, qkvw, wqk_b, wv_b, wow, wow_b);
  rms_mod_kernel<<<dim3(16384), dim3(256), 0, stream>>>(x, nw, modbuf, hbuf);
  gemm_qkv_kernel<<<dim3(768), dim3(512), 0, stream>>>(
      hbuf, wqk_b, wv_b, qbuf, kbuf, vtbuf);
  attn_kernel<<<dim3(2048), dim3(256), 0, stream>>>(qbuf, kbuf, vtbuf, abuf);
  gemm_wo_kernel<<<dim3(256), dim3(512), 0, stream>>>(abuf, wow_b, out);
}

// Round 7
// 375.308 us; speedup vs baseline: 1.2120x; 1.0238x over previous
//
#include <hip/hip_runtime.h>
#include <stdint.h>

// ---------- types ----------
typedef __bf16    bf16x8 __attribute__((ext_vector_type(8)));
typedef float     f32x4  __attribute__((ext_vector_type(4)));
typedef _Float16  f16;
typedef _Float16  f16x2  __attribute__((ext_vector_type(2)));
typedef _Float16  f16x4  __attribute__((ext_vector_type(4)));
typedef _Float16  f16x8  __attribute__((ext_vector_type(8)));

#define DEV __device__ __forceinline__

DEV ushort f2bf(float f) {               // RTNE float -> bf16 bits
  union { float f; uint32_t u; } v; v.f = f;
  uint32_t u = v.u;
  return (ushort)((u + 0x7fffu + ((u >> 16) & 1u)) >> 16);
}

DEV f16x2 cvt_pkrtz(float a, float b) {  // v_cvt_pkrtz_f16_f32, bit-cast to f16x2
  return __builtin_bit_cast(f16x2, __builtin_amdgcn_cvt_pkrtz(a, b));
}

// async global->LDS, 16B per lane. LDS dest must be wave-uniform base + lane*16.
DEV void async16(const void* g, void* l) {
  __builtin_amdgcn_global_load_lds(
      (__attribute__((address_space(1))) void*)(uintptr_t)g,
      (__attribute__((address_space(3))) void*)(uint32_t)(uintptr_t)l,
      16, 0, 0);
}

// ---------- prep kernel: mod-gemm + weight split/cast + wo cast (one launch) ----
__global__ __launch_bounds__(256)
void prep_kernel(const float* __restrict__ t, const float* __restrict__ mw,
                 float* __restrict__ mod,
                 const float* __restrict__ qkvw, ushort* __restrict__ wqk,
                 ushort* __restrict__ wv,
                 const float* __restrict__ wow, ushort* __restrict__ wowb) {
  const int id = blockIdx.x;
  const int tid = threadIdx.x;
  if (id < 2048) {
    // mod = t @ mod_w.T : column j, wave w handles batches w*4..w*4+3
    const int j = id;
    const int w = tid >> 6, lane = tid & 63;
    float wr[16];
#pragma unroll
    for (int i = 0; i < 16; ++i) wr[i] = mw[(size_t)j * 1024 + lane + i * 64];
#pragma unroll
    for (int bb = 0; bb < 4; ++bb) {
      int b = w * 4 + bb;
      float s = 0.f;
#pragma unroll
      for (int i = 0; i < 16; ++i) s += wr[i] * t[b * 1024 + lane + i * 64];
#pragma unroll
      for (int m = 32; m >= 1; m >>= 1) s += __shfl_xor(s, m, 64);
      if (lane == 0) mod[b * 2048 + j] = s;
    }
  } else if (id < 5120) {
    // split qkv_w row j -> wqk (q,k interleaved per head) or wv
    const int j = id - 2048;
    uint32_t hd = (uint32_t)j / 192u;
    uint32_t rem = (uint32_t)j - hd * 192u;
    ushort* dst = (rem < 128u) ? (wqk + (size_t)(hd * 128u + rem) * 1024)
                               : (wv + (size_t)(hd * 64u + (rem - 128u)) * 1024);
    float4 v = ((const float4*)(qkvw + (size_t)j * 1024))[tid];
    ushort4 o;
    o.x = f2bf(v.x); o.y = f2bf(v.y); o.z = f2bf(v.z); o.w = f2bf(v.w);
    ((ushort4*)dst)[tid] = o;
  } else {
    // wo cast: 1024 blocks x 256 thr x float4
    const int i = (id - 5120) * 256 + tid;   // < 262144
    float4 v = ((const float4*)wow)[i];
    ushort4 o;
    o.x = f2bf(v.x); o.y = f2bf(v.y); o.z = f2bf(v.z); o.w = f2bf(v.w);
    ((ushort4*)wowb)[i] = o;
  }
}

// ---------- RMSNorm + modulate -> bf16 h ----------
__global__ __launch_bounds__(256)
void rms_mod_kernel(const float* __restrict__ x, const float* __restrict__ nw,
                    const float* __restrict__ mod, ushort* __restrict__ h) {
  int row = blockIdx.x;
  int b = row >> 10;
  int tid = threadIdx.x;
  const float4 xv = *(const float4*)(x + (size_t)row * 1024 + tid * 4);
  float ss = xv.x * xv.x + xv.y * xv.y + xv.z * xv.z + xv.w * xv.w;
#pragma unroll
  for (int m = 32; m >= 1; m >>= 1) ss += __shfl_xor(ss, m, 64);
  __shared__ float red[4];
  int w = tid >> 6, lane = tid & 63;
  if (lane == 0) red[w] = ss;
  __syncthreads();
  float tot = red[0] + red[1] + red[2] + red[3];
  float rn = rsqrtf(tot * (1.f / 1024.f) + 1e-6f);
  float4 wv = *(const float4*)(nw + tid * 4);
  float4 sc = *(const float4*)(mod + (size_t)b * 2048 + tid * 4);
  float4 sh = *(const float4*)(mod + (size_t)b * 2048 + 1024 + tid * 4);
  ushort4 o;
  o.x = f2bf(xv.x * rn * wv.x * (1.f + sc.x) + sh.x);
  o.y = f2bf(xv.y * rn * wv.y * (1.f + sc.y) + sh.y);
  o.z = f2bf(xv.z * rn * wv.z * (1.f + sc.z) + sh.z);
  o.w = f2bf(xv.w * rn * wv.w * (1.f + sc.w) + sh.w);
  *(ushort4*)(h + (size_t)row * 1024 + tid * 4) = o;
}

// ---------- shared GEMM helpers ----------
DEV void lda2(bf16x8 (&af)[4][2], const ushort* base, const int (&aoff)[2]) {
#pragma unroll
  for (int mf = 0; mf < 4; ++mf)
#pragma unroll
    for (int kk = 0; kk < 2; ++kk)
      af[mf][kk] = *(const bf16x8*)(base + mf * 1024 + aoff[kk]);
}
#define PRIO1 __builtin_amdgcn_s_setprio(1)
#define PRIO0 __builtin_amdgcn_s_setprio(0)

// ---------- QKV GEMM v5: 256x256, BK=64, 8 waves, 1 barrier per K-tile -------
// mode1 = q/k proj + fused RoPE, mode2 = V^T.  C[M][N] = A[M][K] * B[N][K]^T.
// Per tile: stage next tile (other buffer) at top, B strip persistent in regs
// (8 reads), A halves 8+8, two 32-MFMA clusters, ONE __syncthreads (its
// vmcnt(0) drains stages issued a full tile earlier). No intra-tile barriers:
// waves desync so one wave's ds_reads overlap another's MFMAs.
__global__ __launch_bounds__(512, 2)
void gemm_qkv_kernel(const ushort* __restrict__ hbuf, const ushort* __restrict__ wqk,
                     const ushort* __restrict__ wvw,
                     f16* __restrict__ qb, f16* __restrict__ kb,
                     f16* __restrict__ vtb) {
  __shared__ ushort smem[65536];          // 128 KB
  const int id0 = blockIdx.x;
  const int id = (id0 & 7) * 96 + (id0 >> 3);   // XCD swizzle (768 % 8 == 0)
  int mode, m0, n0;
  const ushort *A, *B;
  if (id < 512) {                         // q/k: M=16384 tokens, N=2048 qk-rows
    mode = 1; m0 = (id >> 3) * 256; n0 = (id & 7) * 256; A = hbuf; B = wqk;
  } else {                                // V^T: M=1024 features, N=16384 tokens
    const int i2 = id - 512;
    mode = 2; n0 = (i2 >> 2) * 256; m0 = (i2 & 3) * 256; A = wvw; B = hbuf;
  }
  const int tid = threadIdx.x;
  const int w = tid >> 6, lane = tid & 63, quad = lane >> 4, l15 = lane & 15;
  const int wm = w >> 2, wn = w & 3;      // 2 x 4 wave grid; per-wave C: 128x64

  const int srow = tid >> 3;
  const int sch  = (tid & 7) ^ (srow & 7);
  const int soff = srow * 1024 + sch * 8;           // elems into operand panel
  const ushort* const Abase = A + (size_t)m0 * 1024;
  const ushort* const Bbase = B + (size_t)n0 * 1024;
  ushort* const As0 = smem;                         // 2 bufs x 16384 ushort
  ushort* const Bs0 = smem + 32768;
  const int sdst = tid * 8;                         // ushort offset, lane*16B

#define STG_A(d, t, h) do { \
    async16(Abase + (h) * 131072 + soff + (t) * 64,          As0 + (d) * 16384 + (h) * 8192 + sdst); \
    async16(Abase + (h) * 131072 + 65536 + soff + (t) * 64,  As0 + (d) * 16384 + (h) * 8192 + 4096 + sdst); } while (0)
#define STG_B(d, t, h) do { \
    async16(Bbase + (h) * 131072 + soff + (t) * 64,          Bs0 + (d) * 16384 + (h) * 8192 + sdst); \
    async16(Bbase + (h) * 131072 + 65536 + soff + (t) * 64,  Bs0 + (d) * 16384 + (h) * 8192 + 4096 + sdst); } while (0)

  int aoff[2], boff[2];
#pragma unroll
  for (int kk = 0; kk < 2; ++kk) {
    const int swz = (((kk * 4 + quad) ^ (l15 & 7)) * 8);
    aoff[kk] = (wm * 128 + l15) * 64 + swz;
    boff[kk] = (wn * 64 + l15) * 64 + swz;
  }

  const f32x4 fzero = {0.f, 0.f, 0.f, 0.f};
  f32x4 acc[8][4];
#pragma unroll
  for (int a = 0; a < 8; ++a)
#pragma unroll
    for (int b = 0; b < 4; ++b) acc[a][b] = fzero;

  bf16x8 af[4][2];    // current A half (32 VGPR)
  bf16x8 bfp[4][2];   // B strip persistent (32 VGPR)

  // prologue: stage tile 0 into buf0; syncthreads drains (vmcnt0) + barrier
  STG_A(0, 0, 0); STG_A(0, 0, 1); STG_B(0, 0, 0); STG_B(0, 0, 1);
  __syncthreads();

#pragma unroll 2
  for (int t = 0; t < 16; ++t) {
    const int cur = t & 1, nxt = cur ^ 1;
    const int tn = (t < 15) ? t + 1 : 15;   // last iter re-stages harmlessly
    const ushort* Asc = As0 + cur * 16384;
    const ushort* Bsc = Bs0 + cur * 16384;

    // stage next tile into other buffer: legal (all waves' reads of buf[nxt]
    // preceded the previous __syncthreads)
    STG_A(nxt, tn, 0); STG_A(nxt, tn, 1);
    STG_B(nxt, tn, 0); STG_B(nxt, tn, 1);

    // B strip (8 reads) + A half 0 (8 reads) -> 32 MFMA
#pragma unroll
    for (int nf = 0; nf < 4; ++nf)
#pragma unroll
      for (int kk = 0; kk < 2; ++kk)
        bfp[nf][kk] = *(const bf16x8*)(Bsc + nf * 1024 + boff[kk]);
    lda2(af, Asc, aoff);
    PRIO1;
#pragma unroll
    for (int mf = 0; mf < 4; ++mf)
#pragma unroll
      for (int nf = 0; nf < 4; ++nf)
#pragma unroll
        for (int kk = 0; kk < 2; ++kk)
          acc[mf][nf] = __builtin_amdgcn_mfma_f32_16x16x32_bf16(
              af[mf][kk], bfp[nf][kk], acc[mf][nf], 0, 0, 0);
    PRIO0;
    // A half 1 (8 reads) -> 32 MFMA
    lda2(af, Asc + 4096, aoff);
    PRIO1;
#pragma unroll
    for (int mf = 0; mf < 4; ++mf)
#pragma unroll
      for (int nf = 0; nf < 4; ++nf)
#pragma unroll
        for (int kk = 0; kk < 2; ++kk)
          acc[4 + mf][nf] = __builtin_amdgcn_mfma_f32_16x16x32_bf16(
              af[mf][kk], bfp[nf][kk], acc[4 + mf][nf], 0, 0, 0);
    PRIO0;
    __syncthreads();   // vmcnt(0): next tile landed (issued a full tile ago)
  }
#undef STG_A
#undef STG_B

  // ---- epilogue: wave-private LDS transpose (128x64) -> full-line stores ----
  ushort* eps = smem + w * 8192;          // 16 KB per wave
#pragma unroll
  for (int mf = 0; mf < 8; ++mf)
#pragma unroll
    for (int nf = 0; nf < 4; ++nf)
#pragma unroll
      for (int r = 0; r < 4; ++r) {
        const int row_loc = mf * 16 + quad * 4 + r;
        const int col = nf * 16 + l15;
        const int ch = (col >> 3) ^ (row_loc & 7);
        union { f16 h; ushort u; } cv;
        cv.h = (f16)acc[mf][nf][r];
        eps[row_loc * 64 + ch * 8 + (col & 7)] = cv.u;
      }

  const int ch = lane & 7;
  const int rbase = lane >> 3;
  const int gcol = n0 + wn * 64;
  if (mode == 1) {
    const int hd = gcol >> 7, part = (gcol >> 6) & 1;
    const float QS = part ? 1.f : 0.125f * 1.44269504f;   // q: scale*log2e fold
    f16* const outp = part ? kb : qb;
    float th[4];
#pragma unroll
    for (int t2 = 0; t2 < 4; ++t2)
      th[t2] = __expf(-(float)((ch * 4 + t2) & 15) * 0.5756462732485114f); // ln(1e4)/16
#pragma unroll
    for (int i = 0; i < 16; ++i) {
      const int row_loc = i * 8 + rbase;
      union { uint4 u4; f16 h[8]; } uv;
      uv.u4 = *(const uint4*)(eps + row_loc * 64 + ((ch ^ (row_loc & 7)) * 8));
      const int m = m0 + wm * 128 + row_loc;   // token index
      const int n = m & 1023;
      const float xpos = (float)(n & 31), ypos = (float)(n >> 5);
#pragma unroll
      for (int t2 = 0; t2 < 4; ++t2) {
        const int p = ch * 4 + t2;
        const float pos = (p < 16) ? xpos : ypos;
        float sn, cs;
        __sincosf(pos * th[t2], &sn, &cs);
        const float x0 = (float)uv.h[2 * t2], x1 = (float)uv.h[2 * t2 + 1];
        f16x2 ro = cvt_pkrtz((x0 * cs - x1 * sn) * QS, (x1 * cs + x0 * sn) * QS);
        uv.h[2 * t2] = ro[0];
        uv.h[2 * t2 + 1] = ro[1];
      }
      f16* dst = outp + (((size_t)((m >> 10) * 16 + hd) * 1024 + n) * 64 + ch * 8);
      *(uint4*)dst = uv.u4;
    }
  } else {
    // V^T store with 8B-half swap on rows with bit3 set (attn V bank-conflict
    // fix: LDS read uses half-bit (quad&1)^((d>>3)&1); swap here compensates).
    const int b = gcol >> 10, tb = gcol & 1023;
#pragma unroll
    for (int i = 0; i < 16; ++i) {
      const int row_loc = i * 8 + rbase;
      uint4 v = *(const uint4*)(eps + row_loc * 64 + ((ch ^ (row_loc & 7)) * 8));
      if (i & 1) { unsigned t0 = v.x, t1 = v.y; v.x = v.z; v.y = v.w; v.z = t0; v.w = t1; }
      const int m = m0 + wm * 128 + row_loc;   // feature row
      f16* dst = vtb + ((size_t)(b * 1024 + m) * 1024 + tb + ch * 8);
      *(uint4*)dst = v;
    }
  }
}

// ---------- WO GEMM v3: 256x256, BK=64(=head), 8 waves, 1 barrier per tile ----
// out[16384][1024] fp32 = abuf(head-major) @ wow^T. Grid = 256 blocks = 1/CU.
__global__ __launch_bounds__(512, 2)
void gemm_wo_kernel(const ushort* __restrict__ A, const ushort* __restrict__ B,
                    float* __restrict__ outf) {
  __shared__ ushort smem[65536];          // 128 KB
  const int id0 = blockIdx.x;
  const int id = (id0 & 7) * 32 + (id0 >> 3);   // XCD swizzle (256 % 8 == 0)
  const int m0 = (id >> 2) * 256, n0 = (id & 3) * 256;
  const int tid = threadIdx.x;
  const int w = tid >> 6, lane = tid & 63, quad = lane >> 4, l15 = lane & 15;
  const int wm = w >> 2, wn = w & 3;

  const int srow = tid >> 3;
  const int sch  = (tid & 7) ^ (srow & 7);
  const int soff = srow * 1024 + sch * 8;
  const int b0 = m0 >> 10, nb = m0 & 1023;
  const ushort* const Abase = A + (size_t)b0 * 16 * 65536 + (size_t)nb * 64;
  const ushort* const Bbase = B + (size_t)n0 * 1024;
  ushort* const As0 = smem;
  ushort* const Bs0 = smem + 32768;
  const int sdst = tid * 8;

#define STG_A(d, t, h) do { \
    async16(Abase + (size_t)(t) * 65536 + ((h) * 128 + srow) * 64 + sch * 8,      As0 + (d) * 16384 + (h) * 8192 + sdst); \
    async16(Abase + (size_t)(t) * 65536 + ((h) * 128 + 64 + srow) * 64 + sch * 8, As0 + (d) * 16384 + (h) * 8192 + 4096 + sdst); } while (0)
#define STG_B(d, t, h) do { \
    async16(Bbase + (h) * 131072 + soff + (t) * 64,          Bs0 + (d) * 16384 + (h) * 8192 + sdst); \
    async16(Bbase + (h) * 131072 + 65536 + soff + (t) * 64,  Bs0 + (d) * 16384 + (h) * 8192 + 4096 + sdst); } while (0)

  int aoff[2], boff[2];
#pragma unroll
  for (int kk = 0; kk < 2; ++kk) {
    const int swz = (((kk * 4 + quad) ^ (l15 & 7)) * 8);
    aoff[kk] = (wm * 128 + l15) * 64 + swz;
    boff[kk] = (wn * 64 + l15) * 64 + swz;
  }

  const f32x4 fzero = {0.f, 0.f, 0.f, 0.f};
  f32x4 acc[8][4];
#pragma unroll
  for (int a = 0; a < 8; ++a)
#pragma unroll
    for (int b = 0; b < 4; ++b) acc[a][b] = fzero;

  bf16x8 af[4][2];
  bf16x8 bfp[4][2];
  STG_A(0, 0, 0); STG_A(0, 0, 1); STG_B(0, 0, 0); STG_B(0, 0, 1);
  __syncthreads();

#pragma unroll 2
  for (int t = 0; t < 16; ++t) {
    const int cur = t & 1, nxt = cur ^ 1;
    const int tn = (t < 15) ? t + 1 : 15;
    const ushort* Asc = As0 + cur * 16384;
    const ushort* Bsc = Bs0 + cur * 16384;

    STG_A(nxt, tn, 0); STG_A(nxt, tn, 1);
    STG_B(nxt, tn, 0); STG_B(nxt, tn, 1);
#pragma unroll
    for (int nf = 0; nf < 4; ++nf)
#pragma unroll
      for (int kk = 0; kk < 2; ++kk)
        bfp[nf][kk] = *(const bf16x8*)(Bsc + nf * 1024 + boff[kk]);
    lda2(af, Asc, aoff);
    PRIO1;
#pragma unroll
    for (int mf = 0; mf < 4; ++mf)
#pragma unroll
      for (int nf = 0; nf < 4; ++nf)
#pragma unroll
        for (int kk = 0; kk < 2; ++kk)
          acc[mf][nf] = __builtin_amdgcn_mfma_f32_16x16x32_bf16(
              af[mf][kk], bfp[nf][kk], acc[mf][nf], 0, 0, 0);
    PRIO0;
    lda2(af, Asc + 4096, aoff);
    PRIO1;
#pragma unroll
    for (int mf = 0; mf < 4; ++mf)
#pragma unroll
      for (int nf = 0; nf < 4; ++nf)
#pragma unroll
        for (int kk = 0; kk < 2; ++kk)
          acc[4 + mf][nf] = __builtin_amdgcn_mfma_f32_16x16x32_bf16(
              af[mf][kk], bfp[nf][kk], acc[4 + mf][nf], 0, 0, 0);
    PRIO0;
    __syncthreads();
  }
#undef STG_A
#undef STG_B

  // epilogue: direct fp32 stores (final output)
#pragma unroll
  for (int mf = 0; mf < 8; ++mf)
#pragma unroll
    for (int nf = 0; nf < 4; ++nf) {
      const int col = n0 + wn * 64 + nf * 16 + l15;
#pragma unroll
      for (int r = 0; r < 4; ++r) {
        const int row = m0 + wm * 128 + mf * 16 + quad * 4 + r;
        outf[(size_t)row * 1024 + col] = acc[mf][nf][r];
      }
    }
}

// ---------- flash attention v4: bias-folded softmax, fdot2 sums, deferred l ----
__global__ __launch_bounds__(256, 4)
void attn_kernel(const f16* __restrict__ qbuf, const f16* __restrict__ kbuf,
                 const f16* __restrict__ vtbuf, ushort* __restrict__ aout) {
  __shared__ f16 Ks[2][64 * 64];   // [buf][krow][64d], chunk c ^ (row&7)
  __shared__ f16 Vs[2][64 * 64];   // [buf] V^T [d][64k], chunk c ^ (row&7),
                                   //   8B-half pre-swapped in global for d bit3

  const int id = blockIdx.x;
  const int xcd = id & 7, j = id >> 3;
  const int bh = xcd * 32 + (j >> 3);
  const int q0 = (j & 7) * 128;
  const f16* Qg = qbuf + (size_t)bh * 1024 * 64;
  const f16* Kg = kbuf + (size_t)bh * 1024 * 64;
  const f16* Vg = vtbuf + (size_t)bh * 64 * 1024;
  const int tid = threadIdx.x;
  const int w = tid >> 6, lane = tid & 63, quad = lane >> 4, l15 = lane & 15;
  const f32x4 fzero = {0.f, 0.f, 0.f, 0.f};
  const f16x2 one2 = {(_Float16)1.f, (_Float16)1.f};

  // Q B-fragments (x32 layout): B[n=q=l15][k = dc*32 + quad*8 + i]
  f16x8 qf[2][2];
#pragma unroll
  for (int qs = 0; qs < 2; ++qs)
#pragma unroll
    for (int dc = 0; dc < 2; ++dc)
      qf[qs][dc] = *(const f16x8*)(Qg + (size_t)(q0 + w * 32 + qs * 16 + l15) * 64 +
                                   dc * 32 + quad * 8);

  f32x4 oacc[2][4];
#pragma unroll
  for (int qs = 0; qs < 2; ++qs)
#pragma unroll
    for (int ds = 0; ds < 4; ++ds) oacc[qs][ds] = fzero;
  // mrun = current bias folded into sacc C-init; lrun = per-lane PARTIAL sums
  // (cross-quad reduction deferred to epilogue; alpha is quad-uniform per row).
  float mrun[2] = {0.f, 0.f}, lrun[2] = {0.f, 0.f};

  // prologue: stage tile 0 (K 8KB + V 8KB, 2+2 async16/lane)
#pragma unroll
  for (int i = 0; i < 2; ++i) {
    int u = i * 256 + tid, r = u >> 3, c = u & 7;
    async16(Kg + (size_t)r * 64 + (c ^ (r & 7)) * 8, &Ks[0][u * 8]);
  }
#pragma unroll
  for (int i = 0; i < 2; ++i) {
    int u = i * 256 + tid, r = u >> 3, c = u & 7;
    async16(Vg + (size_t)r * 1024 + (c ^ (r & 7)) * 8, &Vs[0][u * 8]);
  }
  __syncthreads();

#pragma unroll 2
  for (int kt = 0; kt < 1024; kt += 64) {
    const int cur = (kt >> 6) & 1;
    // prefetch next tile into other buffer
    if (kt + 64 < 1024) {
      const int nkt = kt + 64;
#pragma unroll
      for (int i = 0; i < 2; ++i) {
        int u = i * 256 + tid, r = u >> 3, c = u & 7;
        async16(Kg + (size_t)(nkt + r) * 64 + (c ^ (r & 7)) * 8, &Ks[cur ^ 1][u * 8]);
      }
#pragma unroll
      for (int i = 0; i < 2; ++i) {
        int u = i * 256 + tid, r = u >> 3, c = u & 7;
        async16(Vg + (size_t)r * 1024 + nkt + (c ^ (r & 7)) * 8, &Vs[cur ^ 1][u * 8]);
      }
    }
    const f16* Ksc = Ks[cur];
    const f16* Vsc = Vs[cur];

    // S^T = K Q^T via 16x16x32, C-init = -mrun (bias folded: sacc = s - mrun).
    // D[kv=quad*4+r][q=l15]; all 4 D regs of a lane share q -> scalar bias OK.
    f32x4 sacc[2][4];
#pragma unroll
    for (int qs = 0; qs < 2; ++qs) {
      const float nb = -mrun[qs];
      const f32x4 binit = {nb, nb, nb, nb};
#pragma unroll
      for (int ks = 0; ks < 4; ++ks) sacc[qs][ks] = binit;
    }
#pragma unroll
    for (int ks = 0; ks < 4; ++ks) {
#pragma unroll
      for (int dc = 0; dc < 2; ++dc) {
        int row = ks * 16 + l15;
        int ch = (dc * 4 + quad) ^ (row & 7);
        f16x8 kf = *(const f16x8*)(Ksc + row * 64 + ch * 8);
        sacc[0][ks] = __builtin_amdgcn_mfma_f32_16x16x32_f16(kf, qf[0][dc], sacc[0][ks], 0, 0, 0);
        sacc[1][ks] = __builtin_amdgcn_mfma_f32_16x16x32_f16(kf, qf[1][dc], sacc[1][ks], 0, 0, 0);
      }
    }

    // softmax: common path is exp2 directly on biased scores (no subtract);
    // guard keeps p <= 2^8 (f16-safe). Row sums via v_dot2_f32_f16 on the
    // f16-rounded p (numerator/denominator consistent).
    f16x4 pf[2][4];
#pragma unroll
    for (int qs = 0; qs < 2; ++qs) {
      const float* sv = (const float*)&sacc[qs][0];
      float bm = fmaxf(sv[0], sv[1]);
#pragma unroll
      for (int k = 2; k < 16; k += 2)      // v_max3 pairs
        bm = fmaxf(fmaxf(bm, sv[k]), sv[k + 1]);
      bm = fmaxf(bm, __shfl_xor(bm, 16, 64));
      bm = fmaxf(bm, __shfl_xor(bm, 32, 64));   // row max (biased), quad-uniform
      if (__any(bm > 8.f)) {               // rare: rescale path
        const float db = fmaxf(bm, 0.f);   // never rescale up
        const float alpha = __builtin_amdgcn_exp2f(-db);
        mrun[qs] += db;
        lrun[qs] *= alpha;                 // partial sums scale uniformly
        float ar[4];
#pragma unroll
        for (int r = 0; r < 4; ++r) ar[r] = __shfl(alpha, quad * 4 + r, 64);
#pragma unroll
        for (int ds = 0; ds < 4; ++ds)
#pragma unroll
          for (int r = 0; r < 4; ++r) oacc[qs][ds][r] *= ar[r];
#pragma unroll
        for (int ks = 0; ks < 4; ++ks)
#pragma unroll
          for (int r = 0; r < 4; ++r) sacc[qs][ks][r] -= db;
      }
      float rs = lrun[qs];
#pragma unroll
      for (int ks = 0; ks < 4; ++ks) {
        float p0 = __builtin_amdgcn_exp2f(sacc[qs][ks][0]);
        float p1 = __builtin_amdgcn_exp2f(sacc[qs][ks][1]);
        float p2 = __builtin_amdgcn_exp2f(sacc[qs][ks][2]);
        float p3 = __builtin_amdgcn_exp2f(sacc[qs][ks][3]);
        union { f16x4 v; f16x2 h[2]; } pu;
        pu.h[0] = cvt_pkrtz(p0, p1);
        pu.h[1] = cvt_pkrtz(p2, p3);
        pf[qs][ks] = pu.v;
        rs = __builtin_amdgcn_fdot2(pu.h[0], one2, rs, false);
        rs = __builtin_amdgcn_fdot2(pu.h[1], one2, rs, false);
      }
      lrun[qs] = rs;
    }

    // O += P V : P in x16 A layout; V^T B-frag from LDS (conflict-free banks:
    // half-bit = (quad&1) ^ ((d>>3)&1), matches global pre-swap)
#pragma unroll
    for (int ks = 0; ks < 4; ++ks) {
#pragma unroll
      for (int ds = 0; ds < 4; ++ds) {
        int row = ds * 16 + l15;
        int c16 = ks * 2 + (quad >> 1);
        int half = (quad & 1) ^ ((l15 >> 3) & 1);
        f16x4 vf = *(const f16x4*)(Vsc + row * 64 + ((c16 ^ (row & 7)) * 8) + half * 4);
        oacc[0][ds] = __builtin_amdgcn_mfma_f32_16x16x16f16(pf[0][ks], vf, oacc[0][ds], 0, 0, 0);
        oacc[1][ds] = __builtin_amdgcn_mfma_f32_16x16x16f16(pf[1][ks], vf, oacc[1][ds], 0, 0, 0);
      }
    }
    __syncthreads();   // drains prefetch (vmcnt0) + protects buffer swap
  }

  // epilogue: reduce deferred l partials, O /= l -> bf16 via LDS transpose
  // head-major out: aout[(bh*1024 + n)*64 + d]
#pragma unroll
  for (int qs = 0; qs < 2; ++qs) {
    lrun[qs] += __shfl_xor(lrun[qs], 16, 64);
    lrun[qs] += __shfl_xor(lrun[qs], 32, 64);
  }
  ushort* eps = (ushort*)&Ks[0][0] + w * 2048;   // 4KB per wave = 16KB = Ks
#pragma unroll
  for (int qs = 0; qs < 2; ++qs) {
    float linv[4];
#pragma unroll
    for (int r = 0; r < 4; ++r)
      linv[r] = __builtin_amdgcn_rcpf(__shfl(lrun[qs], quad * 4 + r, 64));
#pragma unroll
    for (int ds = 0; ds < 4; ++ds)
#pragma unroll
      for (int r = 0; r < 4; ++r) {
        int row_loc = qs * 16 + quad * 4 + r;
        int col = ds * 16 + l15;
        int ch = (col >> 3) ^ (row_loc & 7);
        eps[row_loc * 64 + ch * 8 + (col & 7)] = f2bf(oacc[qs][ds][r] * linv[r]);
      }
  }
  __syncthreads();
  const size_t obase = ((size_t)bh * 1024 + q0 + w * 32) * 64;
#pragma unroll
  for (int i = 0; i < 4; ++i) {
    int row_loc = i * 8 + (lane >> 3);
    int ch = lane & 7;
    uint4 v = *(const uint4*)(eps + row_loc * 64 + ((ch ^ (row_loc & 7)) * 8));
    *(uint4*)(aout + obase + row_loc * 64 + ch * 8) = v;
  }
}

// ---------- launch ----------
extern "C" void kernel_launch(void* const* d_in, const int* in_sizes, int n_in,
                              void* d_out, int out_size, void* d_ws, size_t ws_size,
                              hipStream_t stream) {
  const float* x    = (const float*)d_in[0];
  const float* t    = (const float*)d_in[1];
  const float* nw   = (const float*)d_in[2];
  const float* mw   = (const float*)d_in[3];
  const float* qkvw = (const float*)d_in[4];
  const float* wow  = (const float*)d_in[5];
  float* out = (float*)d_out;
  char* ws = (char*)d_ws;

  float*  modbuf  = (float*)(ws);                    // 131072 B
  ushort* hbuf    = (ushort*)(ws + 131072);          // 32 MB (bf16)
  ushort* wqk_b   = (ushort*)(ws + 33685504);        // 4 MB
  ushort* wv_b    = (ushort*)(ws + 37879808);        // 2 MB
  ushort* wow_b   = (ushort*)(ws + 39976960);        // 2 MB
  f16*    qbuf    = (f16*)(ws + 42074112);           // 32 MB (rope+scale applied)
  f16*    kbuf    = (f16*)(ws + 75628544);           // 32 MB (rope applied)
  f16*    vtbuf   = (f16*)(ws + 109182976);          // 32 MB (V^T, half-swapped rows)
  ushort* abuf    = (ushort*)(ws + 142737408);       // 32 MB (bf16, head-major)

  prep_kernel<<<dim3(6144), dim3(256), 0, stream>>>(
      t, mw, modbuf, qkvw, wqk_b, wv_b, wow, wow_b);
  rms_mod_kernel<<<dim3(16384), dim3(256), 0, stream>>>(x, nw, modbuf, hbuf);
  gemm_qkv_kernel<<<dim3(768), dim3(512), 0, stream>>>(
      hbuf, wqk_b, wv_b, qbuf, kbuf, vtbuf);
  attn_kernel<<<dim3(2048), dim3(256), 0, stream>>>(qbuf, kbuf, vtbuf, abuf);
  gemm_wo_kernel<<<dim3(256), dim3(512), 0, stream>>>(abuf, wow_b, out);
}